// Round 1
// baseline (1036.127 us; speedup 1.0000x reference)
//
#include <hip/hip_runtime.h>
#include <hip/hip_bf16.h>

using s16x8 = __attribute__((ext_vector_type(8))) short;   // MFMA bf16 A/B fragment (guide §3)
using f32x4 = __attribute__((ext_vector_type(4))) float;   // MFMA C/D fragment

#define LDST 40   // LDS row stride (ushorts) = 80B: 16B-aligned for b128, <=2-way bank alias

__device__ __forceinline__ ushort f2bf(float f) {
  union { float f; unsigned u; } v; v.f = f;
  unsigned r = v.u + 0x7fffu + ((v.u >> 16) & 1u);   // round-to-nearest-even
  return (ushort)(r >> 16);
}

// C[m][n] (+bias[m]) (+relu) = sum_k opA(A)[m][k] * opB(B)[n][k]
// AKC: A stored [M][K] (lda = row stride), else A stored [K][M] (lda = k-row stride)
// BKC: B stored [N][K] (ldb = row stride), else B stored [K][N] (ldb = k-row stride)
// 128x128 tile, 4 waves 2x2, 16x16x32 bf16 MFMA, BK=32. All dims must divide evenly.
template<bool AKC, bool BKC, bool BIAS, bool RELU>
__global__ __launch_bounds__(256, 2)
void gemm_kernel(float* __restrict__ C, const float* __restrict__ A,
                 const float* __restrict__ B, const float* __restrict__ bias,
                 int K, int lda, int ldb, int ldc, long sA, long sB, long sC)
{
  __shared__ ushort As[128 * LDST];
  __shared__ ushort Bs[128 * LDST];
  const int tid = threadIdx.x;
  const int m0 = blockIdx.y * 128, n0 = blockIdx.x * 128;
  A += (long)blockIdx.z * sA; B += (long)blockIdx.z * sB; C += (long)blockIdx.z * sC;

  const int lane = tid & 63, wid = tid >> 6;
  const int wm = (wid >> 1) * 64, wn = (wid & 1) * 64;
  const int fr = lane & 15, kg = lane >> 4;

  f32x4 acc[4][4];
#pragma unroll
  for (int i = 0; i < 4; ++i)
#pragma unroll
    for (int j = 0; j < 4; ++j)
#pragma unroll
      for (int r = 0; r < 4; ++r) acc[i][j][r] = 0.f;

  for (int k0 = 0; k0 < K; k0 += 32) {
    // ---- stage A tile -> As[row_local][k_local] (bf16) ----
    if constexpr (AKC) {
#pragma unroll
      for (int i = 0; i < 4; ++i) {
        int idx = tid + i * 256;            // 1024 float4 quads: 128 rows x 8
        int r = idx >> 3, q = idx & 7;
        float4 f = *(const float4*)(A + (long)(m0 + r) * lda + k0 + q * 4);
        ushort4 u; u.x = f2bf(f.x); u.y = f2bf(f.y); u.z = f2bf(f.z); u.w = f2bf(f.w);
        *(ushort4*)&As[r * LDST + q * 4] = u;
      }
    } else {
#pragma unroll
      for (int i = 0; i < 4; ++i) {
        int idx = tid + i * 256;            // 1024 quads: 128 rows x 8 k-quads
        int rr = idx & 127, kq = idx >> 7;
        ushort4 u;
        u.x = f2bf(A[(long)(k0 + kq * 4 + 0) * lda + m0 + rr]);
        u.y = f2bf(A[(long)(k0 + kq * 4 + 1) * lda + m0 + rr]);
        u.z = f2bf(A[(long)(k0 + kq * 4 + 2) * lda + m0 + rr]);
        u.w = f2bf(A[(long)(k0 + kq * 4 + 3) * lda + m0 + rr]);
        *(ushort4*)&As[rr * LDST + kq * 4] = u;
      }
    }
    // ---- stage B tile -> Bs[col_local][k_local] (bf16) ----
    if constexpr (BKC) {
#pragma unroll
      for (int i = 0; i < 4; ++i) {
        int idx = tid + i * 256;
        int r = idx >> 3, q = idx & 7;
        float4 f = *(const float4*)(B + (long)(n0 + r) * ldb + k0 + q * 4);
        ushort4 u; u.x = f2bf(f.x); u.y = f2bf(f.y); u.z = f2bf(f.z); u.w = f2bf(f.w);
        *(ushort4*)&Bs[r * LDST + q * 4] = u;
      }
    } else {
#pragma unroll
      for (int i = 0; i < 4; ++i) {
        int idx = tid + i * 256;
        int rr = idx & 127, kq = idx >> 7;
        ushort4 u;
        u.x = f2bf(B[(long)(k0 + kq * 4 + 0) * ldb + n0 + rr]);
        u.y = f2bf(B[(long)(k0 + kq * 4 + 1) * ldb + n0 + rr]);
        u.z = f2bf(B[(long)(k0 + kq * 4 + 2) * ldb + n0 + rr]);
        u.w = f2bf(B[(long)(k0 + kq * 4 + 3) * ldb + n0 + rr]);
        *(ushort4*)&Bs[rr * LDST + kq * 4] = u;
      }
    }
    __syncthreads();

    s16x8 af[4], bfv[4];
#pragma unroll
    for (int m = 0; m < 4; ++m)
      af[m] = *(const s16x8*)&As[(wm + m * 16 + fr) * LDST + kg * 8];
#pragma unroll
    for (int n = 0; n < 4; ++n)
      bfv[n] = *(const s16x8*)&Bs[(wn + n * 16 + fr) * LDST + kg * 8];
#pragma unroll
    for (int m = 0; m < 4; ++m)
#pragma unroll
      for (int n = 0; n < 4; ++n)
        acc[m][n] = __builtin_amdgcn_mfma_f32_16x16x32_bf16(af[m], bfv[n], acc[m][n], 0, 0, 0);
    __syncthreads();
  }

  // C/D layout (verified m89/m91): col = lane&15, row = (lane>>4)*4 + reg
#pragma unroll
  for (int m = 0; m < 4; ++m) {
    const int rowb = m0 + wm + m * 16 + kg * 4;
#pragma unroll
    for (int n = 0; n < 4; ++n) {
      const int col = n0 + wn + n * 16 + fr;
#pragma unroll
      for (int r = 0; r < 4; ++r) {
        float v = acc[m][n][r];
        if constexpr (BIAS) v += bias[rowb + r];
        if constexpr (RELU) v = fmaxf(v, 0.f);
        C[(long)(rowb + r) * ldc + col] = v;
      }
    }
  }
}

// In-place row softmax over last dim of [16384][256] (row attn scores; no 1/sqrt scaling per source)
__global__ __launch_bounds__(256)
void softmax_kernel(float* __restrict__ S) {
  const int row = blockIdx.x * 4 + (threadIdx.x >> 6);
  const int lane = threadIdx.x & 63;
  float* p = S + (long)row * 256 + lane * 4;
  float4 v = *(float4*)p;
  float mx = fmaxf(fmaxf(v.x, v.y), fmaxf(v.z, v.w));
#pragma unroll
  for (int off = 32; off; off >>= 1) mx = fmaxf(mx, __shfl_xor(mx, off));
  v.x = __expf(v.x - mx); v.y = __expf(v.y - mx);
  v.z = __expf(v.z - mx); v.w = __expf(v.w - mx);
  float s = v.x + v.y + v.z + v.w;
#pragma unroll
  for (int off = 32; off; off >>= 1) s += __shfl_xor(s, off);
  const float r = 1.f / s;
  v.x *= r; v.y *= r; v.z *= r; v.w *= r;
  *(float4*)p = v;
}

// Column attention: per (h,l): q,k,v are [C=8][S=64]; softmax over key index j.
// One wave per l, 4 l per block (vectorized float4 over l on load/store).
__global__ __launch_bounds__(256)
void colattn_kernel(const float* __restrict__ qkv, float* __restrict__ out) {
  __shared__ float q[4][8][64], kk[4][8][64], vv[4][8][64];
  const int h = blockIdx.y;
  const int l0 = blockIdx.x * 4;
  const int tid = threadIdx.x;
  for (int i = tid; i < 1536; i += 256) {
    int m = i >> 9;              // 0:q 1:k 2:v
    int e = i & 511;             // c*64+s
    int c = e >> 6, s = e & 63;
    float4 f = *(const float4*)(qkv + (long)(m * 512 + h * 8 + c) * 16384 + s * 256 + l0);
    float* dst = (m == 0) ? &q[0][0][0] : (m == 1) ? &kk[0][0][0] : &vv[0][0][0];
    dst[e] = f.x; dst[512 + e] = f.y; dst[1024 + e] = f.z; dst[1536 + e] = f.w;
  }
  __syncthreads();
  const int li = tid >> 6, lane = tid & 63;   // lane = query index i (s)
  float qi[8];
#pragma unroll
  for (int c = 0; c < 8; ++c) qi[c] = q[li][c][lane];
  float sc[64];
#pragma unroll
  for (int j = 0; j < 64; ++j) {
    float s = 0.f;
#pragma unroll
    for (int c = 0; c < 8; ++c) s += qi[c] * kk[li][c][j];   // broadcast reads, conflict-free
    sc[j] = s;
  }
  float mx = sc[0];
#pragma unroll
  for (int j = 1; j < 64; ++j) mx = fmaxf(mx, sc[j]);
  float sum = 0.f;
#pragma unroll
  for (int j = 0; j < 64; ++j) { sc[j] = __expf(sc[j] - mx); sum += sc[j]; }
  const float rs = 1.f / sum;
  float o[8];
#pragma unroll
  for (int c = 0; c < 8; ++c) o[c] = 0.f;
#pragma unroll
  for (int j = 0; j < 64; ++j)
#pragma unroll
    for (int c = 0; c < 8; ++c) o[c] += sc[j] * vv[li][c][j];
  // stash per-wave result in q[] (own slice; own reads long done), then coalesced gather-store
#pragma unroll
  for (int c = 0; c < 8; ++c) q[li][c][lane] = o[c] * rs;
  __syncthreads();
  for (int i = tid; i < 512; i += 256) {
    int c = i >> 6, s = i & 63;
    float4 f; f.x = q[0][c][s]; f.y = q[1][c][s]; f.z = q[2][c][s]; f.w = q[3][c][s];
    *(float4*)(out + (long)(h * 8 + c) * 16384 + s * 256 + l0) = f;
  }
}

// Channel LayerNorm over D=512 at each of 16384 positions. out = LN(a (+ b)) * w + bias.
// Block: 64 positions x 4 d-segments; coalesced along position index.
template<bool RES>
__global__ __launch_bounds__(256)
void ln_kernel(float* __restrict__ out, const float* __restrict__ a,
               const float* __restrict__ b, const float* __restrict__ w,
               const float* __restrict__ bias) {
  __shared__ float red[8][64];
  const int lane = threadIdx.x & 63;
  const int seg = threadIdx.x >> 6;
  const long n = (long)blockIdx.x * 64 + lane;
  float s1 = 0.f, s2 = 0.f;
  for (int d = seg * 128; d < seg * 128 + 128; ++d) {
    float v = a[(long)d * 16384 + n];
    if constexpr (RES) v += b[(long)d * 16384 + n];
    s1 += v; s2 += v * v;
  }
  red[seg][lane] = s1; red[4 + seg][lane] = s2;
  __syncthreads();
  s1 = red[0][lane] + red[1][lane] + red[2][lane] + red[3][lane];
  s2 = red[4][lane] + red[5][lane] + red[6][lane] + red[7][lane];
  const float mean = s1 * (1.f / 512.f);
  const float var = s2 * (1.f / 512.f) - mean * mean;
  const float rstd = rsqrtf(var + 1e-5f);
  for (int d = seg * 128; d < seg * 128 + 128; ++d) {
    float v = a[(long)d * 16384 + n];
    if constexpr (RES) v += b[(long)d * 16384 + n];
    out[(long)d * 16384 + n] = (v - mean) * rstd * w[d] + bias[d];
  }
}

extern "C" void kernel_launch(void* const* d_in, const int* in_sizes, int n_in,
                              void* d_out, int out_size, void* d_ws, size_t ws_size,
                              hipStream_t stream) {
  const float* x     = (const float*)d_in[0];
  const float* w_row = (const float*)d_in[1];
  const float* b_row = (const float*)d_in[2];
  const float* w_col = (const float*)d_in[3];
  const float* b_col = (const float*)d_in[4];
  const float* w_an1 = (const float*)d_in[5];
  const float* b_an1 = (const float*)d_in[6];
  const float* w_an2 = (const float*)d_in[7];
  const float* b_an2 = (const float*)d_in[8];
  const float* w_ff1 = (const float*)d_in[9];
  const float* b_ff1 = (const float*)d_in[10];
  const float* w_ff2 = (const float*)d_in[11];
  const float* b_ff2 = (const float*)d_in[12];
  const float* w_ln1 = (const float*)d_in[13];
  const float* b_ln1 = (const float*)d_in[14];
  const float* w_ln2 = (const float*)d_in[15];
  const float* b_ln2 = (const float*)d_in[16];
  float* outp = (float*)d_out;

  // Workspace (fp32): big region [2048][16384] shared by qkv (1536 rows) / ff1 (2048 rows);
  // scores + attn_out (bufC) live in rows 1536.. (disjoint lifetimes). Total 201.3 MB.
  float* WS   = (float*)d_ws;
  float* qkv  = WS;
  float* sc   = WS + (long)1536 * 16384;            // 64 heads x 256 x 256
  float* bufC = WS + (long)1536 * 16384;            // reused after scores are dead
  float* bufA = WS + (long)2048 * 16384;
  float* bufB = bufA + (long)512 * 16384;

  const dim3 blk(256);
  const long HQ = 131072;  // per-head stride in qkv/out (8 channels * 16384)
  const long HS = 65536;   // per-head stride in scores

  // 1. qkv_row = W_row * x + b_row           [1536][16384]
  gemm_kernel<true, false, true, false><<<dim3(128, 12, 1), blk, 0, stream>>>(
      qkv, w_row, x, b_row, 512, 512, 16384, 16384, 0, 0, 0);
  // 2. scores[h] = Q_h^T K_h                 64 x [256][256], K=512
  gemm_kernel<false, false, false, false><<<dim3(2, 2, 64), blk, 0, stream>>>(
      sc, qkv, qkv + (long)512 * 16384, nullptr, 512, 256, 256, 256, HQ, HQ, HS);
  // 3. softmax over j
  softmax_kernel<<<4096, blk, 0, stream>>>(sc);
  // 4. row_out[h] = V_h * A_h^T              64 x [512][256], K=256  -> bufA (channel-major)
  gemm_kernel<true, true, false, false><<<dim3(2, 4, 64), blk, 0, stream>>>(
      bufA, qkv + (long)1024 * 16384, sc, nullptr, 256, 256, 256, 256, HQ, HS, HQ);
  // 5. out1 = LN(x + row_out)                -> bufB
  ln_kernel<true><<<256, blk, 0, stream>>>(bufB, x, bufA, w_an1, b_an1);
  // 6. qkv_col = W_col * out1 + b_col
  gemm_kernel<true, false, true, false><<<dim3(128, 12, 1), blk, 0, stream>>>(
      qkv, w_col, bufB, b_col, 512, 512, 16384, 16384, 0, 0, 0);
  // 7. col attention                          -> bufA
  colattn_kernel<<<dim3(64, 64), blk, 0, stream>>>(qkv, bufA);
  // 8. attn_out = LN(out1 + col_out)         -> bufC
  ln_kernel<true><<<256, blk, 0, stream>>>(bufC, bufB, bufA, w_an2, b_an2);
  // 9. h = LN(attn_out)                      -> bufB
  ln_kernel<false><<<256, blk, 0, stream>>>(bufB, bufC, nullptr, w_ln1, b_ln1);
  // 10. ff1 = relu(W_ff1 * h + b_ff1)        [2048][16384] (overwrites qkv region)
  gemm_kernel<true, false, true, true><<<dim3(128, 16, 1), blk, 0, stream>>>(
      qkv, w_ff1, bufB, b_ff1, 512, 512, 16384, 16384, 0, 0, 0);
  // 11. ff2 = W_ff2 * ff1 + b_ff2            -> bufA
  gemm_kernel<true, false, true, false><<<dim3(128, 4, 1), blk, 0, stream>>>(
      bufA, w_ff2, qkv, b_ff2, 2048, 2048, 16384, 16384, 0, 0, 0);
  // 12. out = LN(h + ff2)                    -> d_out
  ln_kernel<true><<<256, blk, 0, stream>>>(outp, bufB, bufA, w_ln2, b_ln2);
}

// Round 3
// 531.116 us; speedup vs baseline: 1.9508x; 1.9508x over previous
//
#include <hip/hip_runtime.h>
#include <hip/hip_bf16.h>

using s16x8 = __attribute__((ext_vector_type(8))) short;   // MFMA bf16 A/B fragment
using f32x4 = __attribute__((ext_vector_type(4))) float;   // MFMA C/D fragment
using u32x2 = __attribute__((ext_vector_type(2))) unsigned;

__device__ __forceinline__ ushort f2bf(float f) {
  union { float f; unsigned u; } v; v.f = f;
  unsigned r = v.u + 0x7fffu + ((v.u >> 16) & 1u);   // RNE
  return (ushort)(r >> 16);
}
__device__ __forceinline__ float bf2f(ushort u) {
  return __uint_as_float(((unsigned)u) << 16);
}
__device__ __forceinline__ void gload16(const void* g, void* l) {
  __builtin_amdgcn_global_load_lds(
      (const __attribute__((address_space(1))) void*)g,
      (__attribute__((address_space(3))) void*)l, 16, 0, 0);
}

// ---------------------------------------------------------------------------
// Universal bf16 GEMM: C[m][n] = sum_k A'[m][k] * B'[n][k]
//   form 0 (N-form): operand stored [rows][K] (lda/ldb = row stride), reg-staged
//   form 1 (T-form): operand stored [K][rows] (lda/ldb = k-row stride),
//                    staged via global_load_lds into [nb][32k][16] subtiles,
//                    fragments via ds_read_b64_tr_b16 (HW transpose).
// Both paths use k-map (kg,j) -> {4kg+j, 16+4kg+j}; consistent across A and B,
// so the MFMA k-reduction is unchanged (permutation-invariant).
// 128x128 tile, 4 waves 2x2, BK=32, 1 barrier/iter, stage(t+1) || compute(t).
// OUT: 0 = fp32, 1 = bf16.  TRC: transposed epilogue C[n][m] (contig float4).
// ---------------------------------------------------------------------------
template<int AF, int BF, bool BIAS, bool RELU, int OUT, bool TRC>
__global__ __launch_bounds__(256)
void gemm(void* __restrict__ Cv, const ushort* __restrict__ A,
          const ushort* __restrict__ B, const float* __restrict__ bias,
          int K, int lda, int ldb, int ldc, long sA, long sB, long sC)
{
  __shared__ ushort As[2][5120];   // N-form: [128][40] padded; T-form: [8][512]
  __shared__ ushort Bs[2][5120];
  const int tid  = threadIdx.x;
  const int lane = tid & 63, wid = tid >> 6;
  const int m0 = blockIdx.y * 128, n0 = blockIdx.x * 128;
  A += (long)blockIdx.z * sA;
  B += (long)blockIdx.z * sB;

  const int wm = (wid >> 1) * 64, wn = (wid & 1) * 64;
  const int fr = lane & 15, kg = lane >> 4;

  f32x4 acc[4][4];
#pragma unroll
  for (int i = 0; i < 4; ++i)
#pragma unroll
    for (int j = 0; j < 4; ++j)
#pragma unroll
      for (int r = 0; r < 4; ++r) acc[i][j][r] = 0.f;

  // T-form staging: 8 chunks of [32k][16cols] = 1024B each; 2 gload_lds per wave.
  auto stageT = [&](const ushort* __restrict__ G, int ld, int c0,
                    ushort* lds, int k0) {
#pragma unroll
    for (int c = 0; c < 2; ++c) {
      const int nb = wid * 2 + c;
      const ushort* gp = G + (long)(k0 + (lane >> 1)) * ld + c0 + nb * 16 + (lane & 1) * 8;
      gload16(gp, lds + nb * 512);
    }
  };
  // N-form staging, split into load (early-issue) and LDS write (late).
  auto loadN = [&](const ushort* __restrict__ G, int ld, int r0, int k0,
                   uint4& x, uint4& y) {
    const ushort* gp = G + (long)(r0 + (tid >> 1)) * ld + k0 + (tid & 1) * 8;
    x = *(const uint4*)gp;            // 8 bf16, k-octs {tid&1}
    y = *(const uint4*)(gp + 16);     // k-octs {(tid&1)+2}
  };
  auto writeN = [&](ushort* lds, uint4 x, uint4 y) {
    ushort* p = lds + (tid >> 1) * 40 + (tid & 1) * 8;
    *(uint4*)p = x;
    *(uint4*)(p + 16) = y;
  };
  // Fragment readers (shared permuted k-map).
  auto fragN = [&](const ushort* lds, int row) {
    union { s16x8 f; u32x2 h[2]; } u;
    const ushort* p = lds + row * 40 + kg * 4;
    u.h[0] = *(const u32x2*)p;          // k = 4kg..4kg+3
    u.h[1] = *(const u32x2*)(p + 16);   // k = 16+4kg..+3
    return u.f;
  };
  auto fragT = [&](const ushort* lds, int rb) {
    union { s16x8 f; u32x2 h[2]; } u;
    unsigned base = (unsigned)(unsigned long long)(lds + rb * 512) + lane * 8;
    asm volatile("ds_read_b64_tr_b16 %0, %1" : "=v"(u.h[0]) : "v"(base));
    asm volatile("ds_read_b64_tr_b16 %0, %1 offset:512" : "=v"(u.h[1]) : "v"(base));
    return u.f;
  };

  const int NT = K >> 5;
  uint4 ax, ay, bx, by;

  // prologue: stage tile 0 into buffer 0
  if constexpr (AF == 0) { loadN(A, lda, m0, 0, ax, ay); writeN(As[0], ax, ay); }
  else                   { stageT(A, lda, m0, As[0], 0); }
  if constexpr (BF == 0) { loadN(B, ldb, n0, 0, bx, by); writeN(Bs[0], bx, by); }
  else                   { stageT(B, ldb, n0, Bs[0], 0); }
  __syncthreads();   // drains vmcnt (gload_lds) + lgkm (ds_write)

  for (int t = 0; t < NT; ++t) {
    const int cur = t & 1, nxt = cur ^ 1;
    const bool pre = (t + 1) < NT;
    if (pre) {   // issue next-tile staging before compute (T3/T14)
      if constexpr (AF == 0) loadN(A, lda, m0, (t + 1) << 5, ax, ay);
      else                   stageT(A, lda, m0, As[nxt], (t + 1) << 5);
      if constexpr (BF == 0) loadN(B, ldb, n0, (t + 1) << 5, bx, by);
      else                   stageT(B, ldb, n0, Bs[nxt], (t + 1) << 5);
    }
    s16x8 af[4], bv[4];
#pragma unroll
    for (int m = 0; m < 4; ++m) {
      if constexpr (AF == 0) af[m] = fragN(As[cur], wm + m * 16 + fr);
      else                   af[m] = fragT(As[cur], (wm >> 4) + m);
    }
#pragma unroll
    for (int n = 0; n < 4; ++n) {
      if constexpr (BF == 0) bv[n] = fragN(Bs[cur], wn + n * 16 + fr);
      else                   bv[n] = fragT(Bs[cur], (wn >> 4) + n);
    }
    if constexpr (AF == 1 || BF == 1) {
      asm volatile("s_waitcnt lgkmcnt(0)");     // asm ds_reads: compiler won't wait for us
      __builtin_amdgcn_sched_barrier(0);        // rule #18: pin MFMAs below the wait
    }
    __builtin_amdgcn_s_setprio(1);
#pragma unroll
    for (int m = 0; m < 4; ++m)
#pragma unroll
      for (int n = 0; n < 4; ++n)
        acc[m][n] = __builtin_amdgcn_mfma_f32_16x16x32_bf16(af[m], bv[n], acc[m][n], 0, 0, 0);
    __builtin_amdgcn_s_setprio(0);
    if (pre) {   // late LDS writes for reg-staged operands (auto vmcnt wait on ax..by)
      if constexpr (AF == 0) writeN(As[nxt], ax, ay);
      if constexpr (BF == 0) writeN(Bs[nxt], bx, by);
    }
    __syncthreads();
  }

  // epilogue. C/D layout (m89/m91): col = lane&15, row = (lane>>4)*4 + reg
#pragma unroll
  for (int m = 0; m < 4; ++m) {
    const int rowb = m0 + wm + m * 16 + kg * 4;
#pragma unroll
    for (int n = 0; n < 4; ++n) {
      const int col = n0 + wn + n * 16 + fr;
      f32x4 v = acc[m][n];
      if constexpr (BIAS) {
#pragma unroll
        for (int r = 0; r < 4; ++r) v[r] += bias[rowb + r];
      }
      if constexpr (RELU) {
#pragma unroll
        for (int r = 0; r < 4; ++r) v[r] = fmaxf(v[r], 0.f);
      }
      if constexpr (TRC) {
        float* C = (float*)Cv + (long)blockIdx.z * sC;
        float4 s; s.x = v[0]; s.y = v[1]; s.z = v[2]; s.w = v[3];
        *(float4*)(C + (long)col * ldc + rowb) = s;   // rows contiguous -> float4
      } else if constexpr (OUT == 0) {
        float* C = (float*)Cv + (long)blockIdx.z * sC;
#pragma unroll
        for (int r = 0; r < 4; ++r) C[(long)(rowb + r) * ldc + col] = v[r];
      } else {
        ushort* C = (ushort*)Cv + (long)blockIdx.z * sC;
#pragma unroll
        for (int r = 0; r < 4; ++r) C[(long)(rowb + r) * ldc + col] = f2bf(v[r]);
      }
    }
  }
}

// fp32 -> bf16 bulk convert (weights, x)
__global__ __launch_bounds__(256)
void cvt_kernel(const float4* __restrict__ in, ushort4* __restrict__ out, int n4) {
  int i = blockIdx.x * 256 + threadIdx.x;
  if (i < n4) {
    float4 f = in[i];
    ushort4 u; u.x = f2bf(f.x); u.y = f2bf(f.y); u.z = f2bf(f.z); u.w = f2bf(f.w);
    out[i] = u;
  }
}

// Row softmax over last dim of [16384][256] fp32 scores -> bf16 P
__global__ __launch_bounds__(256)
void softmax_kernel(const float* __restrict__ S, ushort* __restrict__ P) {
  const int row = blockIdx.x * 4 + (threadIdx.x >> 6);
  const int lane = threadIdx.x & 63;
  float4 v = *(const float4*)(S + (long)row * 256 + lane * 4);
  float mx = fmaxf(fmaxf(v.x, v.y), fmaxf(v.z, v.w));
#pragma unroll
  for (int off = 32; off; off >>= 1) mx = fmaxf(mx, __shfl_xor(mx, off));
  v.x = __expf(v.x - mx); v.y = __expf(v.y - mx);
  v.z = __expf(v.z - mx); v.w = __expf(v.w - mx);
  float s = v.x + v.y + v.z + v.w;
#pragma unroll
  for (int off = 32; off; off >>= 1) s += __shfl_xor(s, off);
  const float r = 1.f / s;
  ushort4 o;
  o.x = f2bf(v.x * r); o.y = f2bf(v.y * r); o.z = f2bf(v.z * r); o.w = f2bf(v.w * r);
  *(ushort4*)(P + (long)row * 256 + lane * 4) = o;
}

// Column attention (bf16 qkv in, fp32 out): per (h,l), q,k,v are [C=8][S=64],
// softmax over key index j. One wave per l, 4 l per block.
__global__ __launch_bounds__(256)
void colattn_kernel(const ushort* __restrict__ qkv, float* __restrict__ out) {
  __shared__ float q[4][8][64], kk[4][8][64], vv[4][8][64];
  const int h = blockIdx.y;
  const int l0 = blockIdx.x * 4;
  const int tid = threadIdx.x;
  for (int i = tid; i < 1536; i += 256) {
    int m = i >> 9;              // 0:q 1:k 2:v
    int e = i & 511;             // c*64+s
    int c = e >> 6, s = e & 63;
    ushort4 u = *(const ushort4*)(qkv + (long)(m * 512 + h * 8 + c) * 16384 + s * 256 + l0);
    float* dst = (m == 0) ? &q[0][0][0] : (m == 1) ? &kk[0][0][0] : &vv[0][0][0];
    dst[e] = bf2f(u.x); dst[512 + e] = bf2f(u.y);
    dst[1024 + e] = bf2f(u.z); dst[1536 + e] = bf2f(u.w);
  }
  __syncthreads();
  const int li = tid >> 6, lane = tid & 63;   // lane = query index i (s)
  float qi[8];
#pragma unroll
  for (int c = 0; c < 8; ++c) qi[c] = q[li][c][lane];
  float sc[64];
#pragma unroll
  for (int j = 0; j < 64; ++j) {
    float s = 0.f;
#pragma unroll
    for (int c = 0; c < 8; ++c) s += qi[c] * kk[li][c][j];
    sc[j] = s;
  }
  float mx = sc[0];
#pragma unroll
  for (int j = 1; j < 64; ++j) mx = fmaxf(mx, sc[j]);
  float sum = 0.f;
#pragma unroll
  for (int j = 0; j < 64; ++j) { sc[j] = __expf(sc[j] - mx); sum += sc[j]; }
  const float rs = 1.f / sum;
  float o[8];
#pragma unroll
  for (int c = 0; c < 8; ++c) o[c] = 0.f;
#pragma unroll
  for (int j = 0; j < 64; ++j)
#pragma unroll
    for (int c = 0; c < 8; ++c) o[c] += sc[j] * vv[li][c][j];
#pragma unroll
  for (int c = 0; c < 8; ++c) q[li][c][lane] = o[c] * rs;
  __syncthreads();
  for (int i = tid; i < 512; i += 256) {
    int c = i >> 6, s = i & 63;
    float4 f; f.x = q[0][c][s]; f.y = q[1][c][s]; f.z = q[2][c][s]; f.w = q[3][c][s];
    *(float4*)(out + (long)(h * 8 + c) * 16384 + s * 256 + l0) = f;
  }
}

// Channel LayerNorm over D=512 at 16384 positions. out = LN(a (+ b)) * w + bias.
// Optionally also writes a bf16 copy (next GEMM's input).
template<bool RES, bool BFO>
__global__ __launch_bounds__(256)
void ln_kernel(float* __restrict__ out, ushort* __restrict__ bfo,
               const float* __restrict__ a, const float* __restrict__ b,
               const float* __restrict__ w, const float* __restrict__ bias) {
  __shared__ float red[8][64];
  const int lane = threadIdx.x & 63;
  const int seg = threadIdx.x >> 6;
  const long n = (long)blockIdx.x * 64 + lane;
  float s1 = 0.f, s2 = 0.f;
  for (int d = seg * 128; d < seg * 128 + 128; ++d) {
    float v = a[(long)d * 16384 + n];
    if constexpr (RES) v += b[(long)d * 16384 + n];
    s1 += v; s2 += v * v;
  }
  red[seg][lane] = s1; red[4 + seg][lane] = s2;
  __syncthreads();
  s1 = red[0][lane] + red[1][lane] + red[2][lane] + red[3][lane];
  s2 = red[4][lane] + red[5][lane] + red[6][lane] + red[7][lane];
  const float mean = s1 * (1.f / 512.f);
  const float var = s2 * (1.f / 512.f) - mean * mean;
  const float rstd = rsqrtf(var + 1e-5f);
  for (int d = seg * 128; d < seg * 128 + 128; ++d) {
    float v = a[(long)d * 16384 + n];
    if constexpr (RES) v += b[(long)d * 16384 + n];
    float o = (v - mean) * rstd * w[d] + bias[d];
    out[(long)d * 16384 + n] = o;
    if constexpr (BFO) bfo[(long)d * 16384 + n] = f2bf(o);
  }
}

extern "C" void kernel_launch(void* const* d_in, const int* in_sizes, int n_in,
                              void* d_out, int out_size, void* d_ws, size_t ws_size,
                              hipStream_t stream) {
  const float* x     = (const float*)d_in[0];
  const float* w_row = (const float*)d_in[1];
  const float* b_row = (const float*)d_in[2];
  const float* w_col = (const float*)d_in[3];
  const float* b_col = (const float*)d_in[4];
  const float* w_an1 = (const float*)d_in[5];
  const float* b_an1 = (const float*)d_in[6];
  const float* w_an2 = (const float*)d_in[7];
  const float* b_an2 = (const float*)d_in[8];
  const float* w_ff1 = (const float*)d_in[9];
  const float* b_ff1 = (const float*)d_in[10];
  const float* w_ff2 = (const float*)d_in[11];
  const float* b_ff2 = (const float*)d_in[12];
  const float* w_ln1 = (const float*)d_in[13];
  const float* b_ln1 = (const float*)d_in[14];
  const float* w_ln2 = (const float*)d_in[15];
  const float* b_ln2 = (const float*)d_in[16];
  float* outp = (float*)d_out;

  // ---- workspace layout (<= 184 MiB; harness gave >= 192 MiB in round 0) ----
  char* Wb = (char*)d_ws;
  ushort* big   = (ushort*)Wb;                              // [2048][16384] bf16: qkv, then ff1
  float*  sc    = (float*)(Wb + (size_t)1536 * 16384 * 2);  // scores fp32, inside big rows 1536+
  float*  bufA  = (float*)(Wb + 67108864ull);               // 32 MiB fp32 [512][16384]
  float*  bufB  = (float*)(Wb + 100663296ull);              // 32 MiB
  float*  bufC  = (float*)(Wb + 134217728ull);              // 32 MiB
  ushort* P     = (ushort*)bufC;                            // bf16 attn probs (dead before LN8)
  ushort* actbf = (ushort*)(Wb + 167772160ull);             // 16 MiB bf16 act (also x_bf: disjoint lifetime)
  ushort* xbf   = actbf;
  ushort* wrowb = (ushort*)(Wb + 184549376ull);
  ushort* wcolb = wrowb + 786432;
  ushort* wff1b = wcolb + 786432;
  ushort* wff2b = wff1b + 1048576;

  const dim3 blk(256);
  const long HQ = 131072;  // per-head stride in qkv (8 ch * 16384)
  const long HS = 65536;   // per-head stride in scores/P

  // 0. bf16 conversions (weights + x)
  cvt_kernel<<<8192, blk, 0, stream>>>((const float4*)x, (ushort4*)xbf, 2097152);
  cvt_kernel<<<768,  blk, 0, stream>>>((const float4*)w_row, (ushort4*)wrowb, 196608);
  cvt_kernel<<<768,  blk, 0, stream>>>((const float4*)w_col, (ushort4*)wcolb, 196608);
  cvt_kernel<<<1024, blk, 0, stream>>>((const float4*)w_ff1, (ushort4*)wff1b, 262144);
  cvt_kernel<<<1024, blk, 0, stream>>>((const float4*)w_ff2, (ushort4*)wff2b, 262144);

  // 1. qkv_row = W_row * x + b_row   [1536][16384] bf16
  gemm<0,1,true,false,1,false><<<dim3(128, 12, 1), blk, 0, stream>>>(
      big, wrowb, xbf, b_row, 512, 512, 16384, 16384, 0, 0, 0);
  // 2. scores[h][i][j] = sum_cs Q[cs][i] K[cs][j]   (A,B both T-form)
  gemm<1,1,false,false,0,false><<<dim3(2, 2, 64), blk, 0, stream>>>(
      sc, big, big + (long)512 * 16384, nullptr, 512, 256, 256, 256, HQ, HQ, HS);
  // 3. softmax over j -> bf16 P
  softmax_kernel<<<4096, blk, 0, stream>>>(sc, P);
  // 4. row_out[cs][i] = sum_j P[i][j] V[cs][j]  (both N-form, transposed epilogue)
  gemm<0,0,false,false,0,true><<<dim3(4, 2, 64), blk, 0, stream>>>(
      bufA, P, big + (long)1024 * 16384, nullptr, 256, 256, 256, 256, HS, HQ, HQ);
  // 5. out1 = LN(x + row_out) -> bufB (+ bf16 actbf)
  ln_kernel<true, true><<<256, blk, 0, stream>>>(bufB, actbf, x, bufA, w_an1, b_an1);
  // 6. qkv_col = W_col * out1 + b_col  -> big (bf16)
  gemm<0,1,true,false,1,false><<<dim3(128, 12, 1), blk, 0, stream>>>(
      big, wcolb, actbf, b_col, 512, 512, 16384, 16384, 0, 0, 0);
  // 7. column attention -> bufA (fp32)
  colattn_kernel<<<dim3(64, 64), blk, 0, stream>>>(big, bufA);
  // 8. attn_out = LN(out1 + col_out) -> bufC
  ln_kernel<true, false><<<256, blk, 0, stream>>>(bufC, nullptr, bufB, bufA, w_an2, b_an2);
  // 9. h = LN(attn_out) -> bufB (+ bf16 actbf)
  ln_kernel<false, true><<<256, blk, 0, stream>>>(bufB, actbf, bufC, nullptr, w_ln1, b_ln1);
  // 10. ff1 = relu(W_ff1 * h + b_ff1) -> big [2048][16384] bf16
  gemm<0,1,true,true,1,false><<<dim3(128, 16, 1), blk, 0, stream>>>(
      big, wff1b, actbf, b_ff1, 512, 512, 16384, 16384, 0, 0, 0);
  // 11. ff2 = W_ff2 * ff1 + b_ff2 -> bufA fp32
  gemm<0,1,true,false,0,false><<<dim3(128, 4, 1), blk, 0, stream>>>(
      bufA, wff2b, big, b_ff2, 2048, 2048, 16384, 16384, 0, 0, 0);
  // 12. out = LN(h + ff2) -> d_out
  ln_kernel<true, false><<<256, blk, 0, stream>>>(outp, nullptr, bufB, bufA, w_ln2, b_ln2);
}

// Round 5
// 499.144 us; speedup vs baseline: 2.0758x; 1.0641x over previous
//
#include <hip/hip_runtime.h>
#include <hip/hip_bf16.h>

using s16x8 = __attribute__((ext_vector_type(8))) short;   // MFMA bf16 A/B fragment
using f32x4 = __attribute__((ext_vector_type(4))) float;   // MFMA C/D fragment
using u32x2 = __attribute__((ext_vector_type(2))) unsigned;

__device__ __forceinline__ ushort f2bf(float f) {
  union { float f; unsigned u; } v; v.f = f;
  unsigned r = v.u + 0x7fffu + ((v.u >> 16) & 1u);   // RNE
  return (ushort)(r >> 16);
}
__device__ __forceinline__ float bf2f(ushort u) {
  return __uint_as_float(((unsigned)u) << 16);
}
__device__ __forceinline__ void gload16(const void* g, void* l) {
  __builtin_amdgcn_global_load_lds(
      (const __attribute__((address_space(1))) void*)g,
      (__attribute__((address_space(3))) void*)l, 16, 0, 0);
}

// ---------------------------------------------------------------------------
// Universal bf16 GEMM: C[m][n] = sum_k A'[m][k] * B'[n][k]
//   form 0 (N-form): operand stored [rows][K], reg-staged (T14 split)
//   form 1 (T-form): operand stored [K][rows], global_load_lds -> [nb][32k][16]
//                    subtiles, fragments via ds_read_b64_tr_b16 (HW transpose).
// Both paths share the permuted k-map (kg,j) -> {4kg+j, 16+4kg+j}.
// 128x128 tile, 4 waves 2x2, BK=32, 1 barrier/iter, stage(t+1) || compute(t).
// T1 XCD swizzle on (bx,by) when nwg%8==0 (identity otherwise).
// ---------------------------------------------------------------------------
template<int AF, int BF, bool BIAS, bool RELU, int OUT, bool TRC>
__global__ __launch_bounds__(256)
void gemm(void* __restrict__ Cv, const ushort* __restrict__ A,
          const ushort* __restrict__ B, const float* __restrict__ bias,
          int K, int lda, int ldb, int ldc, long sA, long sB, long sC)
{
  __shared__ ushort As[2][5120];   // N-form: [128][40] padded; T-form: [8][512]
  __shared__ ushort Bs[2][5120];
  const int tid  = threadIdx.x;
  const int lane = tid & 63, wid = tid >> 6;
  // T1: XCD-aware block swizzle (bijective when nwg divisible by 8)
  const int nwg = gridDim.x * gridDim.y;
  const int lin = blockIdx.y * gridDim.x + blockIdx.x;
  const int swz = ((nwg & 7) == 0) ? ((lin & 7) * (nwg >> 3) + (lin >> 3)) : lin;
  const int m0 = (swz / gridDim.x) * 128, n0 = (swz % gridDim.x) * 128;
  A += (long)blockIdx.z * sA;
  B += (long)blockIdx.z * sB;

  const int wm = (wid >> 1) * 64, wn = (wid & 1) * 64;
  const int fr = lane & 15, kg = lane >> 4;

  f32x4 acc[4][4];
#pragma unroll
  for (int i = 0; i < 4; ++i)
#pragma unroll
    for (int j = 0; j < 4; ++j)
#pragma unroll
      for (int r = 0; r < 4; ++r) acc[i][j][r] = 0.f;

  auto stageT = [&](const ushort* __restrict__ G, int ld, int c0,
                    ushort* lds, int k0) {
#pragma unroll
    for (int c = 0; c < 2; ++c) {
      const int nb = wid * 2 + c;
      const ushort* gp = G + (long)(k0 + (lane >> 1)) * ld + c0 + nb * 16 + (lane & 1) * 8;
      gload16(gp, lds + nb * 512);
    }
  };
  auto loadN = [&](const ushort* __restrict__ G, int ld, int r0, int k0,
                   uint4& x, uint4& y) {
    const ushort* gp = G + (long)(r0 + (tid >> 1)) * ld + k0 + (tid & 1) * 8;
    x = *(const uint4*)gp;
    y = *(const uint4*)(gp + 16);
  };
  auto writeN = [&](ushort* lds, uint4 x, uint4 y) {
    ushort* p = lds + (tid >> 1) * 40 + (tid & 1) * 8;
    *(uint4*)p = x;
    *(uint4*)(p + 16) = y;
  };
  auto fragN = [&](const ushort* lds, int row) {
    union { s16x8 f; u32x2 h[2]; } u;
    const ushort* p = lds + row * 40 + kg * 4;
    u.h[0] = *(const u32x2*)p;
    u.h[1] = *(const u32x2*)(p + 16);
    return u.f;
  };
  auto fragT = [&](const ushort* lds, int rb) {
    union { s16x8 f; u32x2 h[2]; } u;
    unsigned base = (unsigned)(unsigned long long)(lds + rb * 512) + lane * 8;
    asm volatile("ds_read_b64_tr_b16 %0, %1" : "=v"(u.h[0]) : "v"(base));
    asm volatile("ds_read_b64_tr_b16 %0, %1 offset:512" : "=v"(u.h[1]) : "v"(base));
    return u.f;
  };

  const int NT = K >> 5;
  uint4 ax, ay, bx, by;

  if constexpr (AF == 0) { loadN(A, lda, m0, 0, ax, ay); writeN(As[0], ax, ay); }
  else                   { stageT(A, lda, m0, As[0], 0); }
  if constexpr (BF == 0) { loadN(B, ldb, n0, 0, bx, by); writeN(Bs[0], bx, by); }
  else                   { stageT(B, ldb, n0, Bs[0], 0); }
  __syncthreads();

  for (int t = 0; t < NT; ++t) {
    const int cur = t & 1, nxt = cur ^ 1;
    const bool pre = (t + 1) < NT;
    if (pre) {
      if constexpr (AF == 0) loadN(A, lda, m0, (t + 1) << 5, ax, ay);
      else                   stageT(A, lda, m0, As[nxt], (t + 1) << 5);
      if constexpr (BF == 0) loadN(B, ldb, n0, (t + 1) << 5, bx, by);
      else                   stageT(B, ldb, n0, Bs[nxt], (t + 1) << 5);
    }
    s16x8 af[4], bv[4];
#pragma unroll
    for (int m = 0; m < 4; ++m) {
      if constexpr (AF == 0) af[m] = fragN(As[cur], wm + m * 16 + fr);
      else                   af[m] = fragT(As[cur], (wm >> 4) + m);
    }
#pragma unroll
    for (int n = 0; n < 4; ++n) {
      if constexpr (BF == 0) bv[n] = fragN(Bs[cur], wn + n * 16 + fr);
      else                   bv[n] = fragT(Bs[cur], (wn >> 4) + n);
    }
    if constexpr (AF == 1 || BF == 1) {
      asm volatile("s_waitcnt lgkmcnt(0)");
      __builtin_amdgcn_sched_barrier(0);        // rule #18
    }
    __builtin_amdgcn_s_setprio(1);
#pragma unroll
    for (int m = 0; m < 4; ++m)
#pragma unroll
      for (int n = 0; n < 4; ++n)
        acc[m][n] = __builtin_amdgcn_mfma_f32_16x16x32_bf16(af[m], bv[n], acc[m][n], 0, 0, 0);
    __builtin_amdgcn_s_setprio(0);
    if (pre) {
      if constexpr (AF == 0) writeN(As[nxt], ax, ay);
      if constexpr (BF == 0) writeN(Bs[nxt], bx, by);
    }
    __syncthreads();
  }

  // epilogue. C/D layout (m89/m91): col = lane&15, row = (lane>>4)*4 + reg
#pragma unroll
  for (int m = 0; m < 4; ++m) {
    const int rowb = m0 + wm + m * 16 + kg * 4;
#pragma unroll
    for (int n = 0; n < 4; ++n) {
      const int col = n0 + wn + n * 16 + fr;
      f32x4 v = acc[m][n];
      if constexpr (BIAS) {
#pragma unroll
        for (int r = 0; r < 4; ++r) v[r] += bias[rowb + r];
      }
      if constexpr (RELU) {
#pragma unroll
        for (int r = 0; r < 4; ++r) v[r] = fmaxf(v[r], 0.f);
      }
      if constexpr (TRC) {
        float* C = (float*)Cv + (long)blockIdx.z * sC;
        float4 s; s.x = v[0]; s.y = v[1]; s.z = v[2]; s.w = v[3];
        *(float4*)(C + (long)col * ldc + rowb) = s;
      } else if constexpr (OUT == 0) {
        float* C = (float*)Cv + (long)blockIdx.z * sC;
#pragma unroll
        for (int r = 0; r < 4; ++r) C[(long)(rowb + r) * ldc + col] = v[r];
      } else {
        ushort* C = (ushort*)Cv + (long)blockIdx.z * sC;
#pragma unroll
        for (int r = 0; r < 4; ++r) C[(long)(rowb + r) * ldc + col] = f2bf(v[r]);
      }
    }
  }
}

// fp32 -> bf16 bulk convert
__global__ __launch_bounds__(256)
void cvt_kernel(const float4* __restrict__ in, ushort4* __restrict__ out, int n4) {
  int i = blockIdx.x * 256 + threadIdx.x;
  if (i < n4) {
    float4 f = in[i];
    ushort4 u; u.x = f2bf(f.x); u.y = f2bf(f.y); u.z = f2bf(f.z); u.w = f2bf(f.w);
    out[i] = u;
  }
}

// Row softmax over last dim of [16384][256] fp32 scores -> bf16 P
__global__ __launch_bounds__(256)
void softmax_kernel(const float* __restrict__ S, ushort* __restrict__ P) {
  const int row = blockIdx.x * 4 + (threadIdx.x >> 6);
  const int lane = threadIdx.x & 63;
  float4 v = *(const float4*)(S + (long)row * 256 + lane * 4);
  float mx = fmaxf(fmaxf(v.x, v.y), fmaxf(v.z, v.w));
#pragma unroll
  for (int off = 32; off; off >>= 1) mx = fmaxf(mx, __shfl_xor(mx, off));
  v.x = __expf(v.x - mx); v.y = __expf(v.y - mx);
  v.z = __expf(v.z - mx); v.w = __expf(v.w - mx);
  float s = v.x + v.y + v.z + v.w;
#pragma unroll
  for (int off = 32; off; off >>= 1) s += __shfl_xor(s, off);
  const float r = 1.f / s;
  ushort4 o;
  o.x = f2bf(v.x * r); o.y = f2bf(v.y * r); o.z = f2bf(v.z * r); o.w = f2bf(v.w * r);
  *(ushort4*)(P + (long)row * 256 + lane * 4) = o;
}

// Column attention with T1 XCD swizzle: blocks sharing cache lines (same head,
// adjacent l) land on the same XCD's L2. grid = 4096 linear.
__global__ __launch_bounds__(256)
void colattn_kernel(const ushort* __restrict__ qkv, float* __restrict__ out) {
  __shared__ float q[4][8][64], kk[4][8][64], vv[4][8][64];
  const int lin = blockIdx.x;
  const int swz = (lin & 7) * 512 + (lin >> 3);   // bijective, 4096 % 8 == 0
  const int h = swz >> 6;
  const int l0 = (swz & 63) * 4;
  const int tid = threadIdx.x;
  for (int i = tid; i < 1536; i += 256) {
    int m = i >> 9;              // 0:q 1:k 2:v
    int e = i & 511;             // c*64+s
    int c = e >> 6, s = e & 63;
    ushort4 u = *(const ushort4*)(qkv + (long)(m * 512 + h * 8 + c) * 16384 + s * 256 + l0);
    float* dst = (m == 0) ? &q[0][0][0] : (m == 1) ? &kk[0][0][0] : &vv[0][0][0];
    dst[e] = bf2f(u.x); dst[512 + e] = bf2f(u.y);
    dst[1024 + e] = bf2f(u.z); dst[1536 + e] = bf2f(u.w);
  }
  __syncthreads();
  const int li = tid >> 6, lane = tid & 63;   // lane = query index i (s)
  float qi[8];
#pragma unroll
  for (int c = 0; c < 8; ++c) qi[c] = q[li][c][lane];
  float sc[64];
#pragma unroll
  for (int j = 0; j < 64; ++j) {
    float s = 0.f;
#pragma unroll
    for (int c = 0; c < 8; ++c) s += qi[c] * kk[li][c][j];
    sc[j] = s;
  }
  float mx = sc[0];
#pragma unroll
  for (int j = 1; j < 64; ++j) mx = fmaxf(mx, sc[j]);
  float sum = 0.f;
#pragma unroll
  for (int j = 0; j < 64; ++j) { sc[j] = __expf(sc[j] - mx); sum += sc[j]; }
  const float rs = 1.f / sum;
  float o[8];
#pragma unroll
  for (int c = 0; c < 8; ++c) o[c] = 0.f;
#pragma unroll
  for (int j = 0; j < 64; ++j)
#pragma unroll
    for (int c = 0; c < 8; ++c) o[c] += sc[j] * vv[li][c][j];
#pragma unroll
  for (int c = 0; c < 8; ++c) q[li][c][lane] = o[c] * rs;
  __syncthreads();
  for (int i = tid; i < 512; i += 256) {
    int c = i >> 6, s = i & 63;
    float4 f; f.x = q[0][c][s]; f.y = q[1][c][s]; f.z = q[2][c][s]; f.w = q[3][c][s];
    *(float4*)(out + (long)(h * 8 + c) * 16384 + s * 256 + l0) = f;
  }
}

// Register-resident channel LN: block=1024 (16 segs x 64 lanes), each thread
// holds its 32-channel slice in VGPRs -> input read ONCE, 16 waves/CU.
template<bool RES, bool BFO>
__global__ __launch_bounds__(1024)
void ln_kernel(float* __restrict__ out, ushort* __restrict__ bfo,
               const float* __restrict__ a, const float* __restrict__ b,
               const float* __restrict__ w, const float* __restrict__ bias) {
  __shared__ float red[2][16][64];
  const int lane = threadIdx.x & 63, seg = threadIdx.x >> 6;
  const long n = (long)blockIdx.x * 64 + lane;
  const int d0 = seg * 32;
  float v[32];
  float s1 = 0.f, s2 = 0.f;
#pragma unroll
  for (int i = 0; i < 32; ++i) {
    float t = a[(long)(d0 + i) * 16384 + n];
    if constexpr (RES) t += b[(long)(d0 + i) * 16384 + n];
    v[i] = t; s1 += t; s2 += t * t;
  }
  red[0][seg][lane] = s1; red[1][seg][lane] = s2;
  __syncthreads();
  s1 = 0.f; s2 = 0.f;
#pragma unroll
  for (int s = 0; s < 16; ++s) { s1 += red[0][s][lane]; s2 += red[1][s][lane]; }
  const float mean = s1 * (1.f / 512.f);
  const float var = s2 * (1.f / 512.f) - mean * mean;
  const float rstd = rsqrtf(var + 1e-5f);
#pragma unroll
  for (int i = 0; i < 32; ++i) {
    float o = (v[i] - mean) * rstd * w[d0 + i] + bias[d0 + i];
    out[(long)(d0 + i) * 16384 + n] = o;
    if constexpr (BFO) bfo[(long)(d0 + i) * 16384 + n] = f2bf(o);
  }
}

// Fused LN8+LN9: h = LN( LN(a+b)*w1+b1 )*w2+b2, written in-place to out (=a ok)
// plus bf16 copy. Removes the bufC round-trip entirely.
__global__ __launch_bounds__(1024)
void ln_fuse_kernel(float* __restrict__ out, ushort* __restrict__ bfo,
                    const float* __restrict__ a, const float* __restrict__ b,
                    const float* __restrict__ w1, const float* __restrict__ b1,
                    const float* __restrict__ w2, const float* __restrict__ b2) {
  __shared__ float red[2][16][64];
  const int lane = threadIdx.x & 63, seg = threadIdx.x >> 6;
  const long n = (long)blockIdx.x * 64 + lane;
  const int d0 = seg * 32;
  float v[32];
  float s1 = 0.f, s2 = 0.f;
#pragma unroll
  for (int i = 0; i < 32; ++i) {
    float t = a[(long)(d0 + i) * 16384 + n] + b[(long)(d0 + i) * 16384 + n];
    v[i] = t; s1 += t; s2 += t * t;
  }
  red[0][seg][lane] = s1; red[1][seg][lane] = s2;
  __syncthreads();
  s1 = 0.f; s2 = 0.f;
#pragma unroll
  for (int s = 0; s < 16; ++s) { s1 += red[0][s][lane]; s2 += red[1][s][lane]; }
  float mean = s1 * (1.f / 512.f);
  float var = s2 * (1.f / 512.f) - mean * mean;
  float rstd = rsqrtf(var + 1e-5f);
  __syncthreads();   // red reuse
  s1 = 0.f; s2 = 0.f;
#pragma unroll
  for (int i = 0; i < 32; ++i) {
    float y = (v[i] - mean) * rstd * w1[d0 + i] + b1[d0 + i];
    v[i] = y; s1 += y; s2 += y * y;
  }
  red[0][seg][lane] = s1; red[1][seg][lane] = s2;
  __syncthreads();
  s1 = 0.f; s2 = 0.f;
#pragma unroll
  for (int s = 0; s < 16; ++s) { s1 += red[0][s][lane]; s2 += red[1][s][lane]; }
  mean = s1 * (1.f / 512.f);
  var = s2 * (1.f / 512.f) - mean * mean;
  rstd = rsqrtf(var + 1e-5f);
#pragma unroll
  for (int i = 0; i < 32; ++i) {
    float o = (v[i] - mean) * rstd * w2[d0 + i] + b2[d0 + i];
    out[(long)(d0 + i) * 16384 + n] = o;
    bfo[(long)(d0 + i) * 16384 + n] = f2bf(o);
  }
}

extern "C" void kernel_launch(void* const* d_in, const int* in_sizes, int n_in,
                              void* d_out, int out_size, void* d_ws, size_t ws_size,
                              hipStream_t stream) {
  const float* x     = (const float*)d_in[0];
  const float* w_row = (const float*)d_in[1];
  const float* b_row = (const float*)d_in[2];
  const float* w_col = (const float*)d_in[3];
  const float* b_col = (const float*)d_in[4];
  const float* w_an1 = (const float*)d_in[5];
  const float* b_an1 = (const float*)d_in[6];
  const float* w_an2 = (const float*)d_in[7];
  const float* b_an2 = (const float*)d_in[8];
  const float* w_ff1 = (const float*)d_in[9];
  const float* b_ff1 = (const float*)d_in[10];
  const float* w_ff2 = (const float*)d_in[11];
  const float* b_ff2 = (const float*)d_in[12];
  const float* w_ln1 = (const float*)d_in[13];
  const float* b_ln1 = (const float*)d_in[14];
  const float* w_ln2 = (const float*)d_in[15];
  const float* b_ln2 = (const float*)d_in[16];
  float* outp = (float*)d_out;

  char* Wb = (char*)d_ws;
  ushort* big   = (ushort*)Wb;                              // [2048][16384] bf16: qkv, then ff1
  float*  sc    = (float*)(Wb + (size_t)1536 * 16384 * 2);  // scores fp32
  float*  bufA  = (float*)(Wb + 67108864ull);               // 32 MiB fp32 [512][16384]
  float*  bufB  = (float*)(Wb + 100663296ull);              // 32 MiB
  ushort* P     = (ushort*)(Wb + 134217728ull);             // bf16 attn probs
  ushort* actbf = (ushort*)(Wb + 167772160ull);             // 16 MiB bf16 act / x_bf
  ushort* xbf   = actbf;
  ushort* wrowb = (ushort*)(Wb + 184549376ull);
  ushort* wcolb = wrowb + 786432;
  ushort* wff1b = wcolb + 786432;
  ushort* wff2b = wff1b + 1048576;

  const dim3 blk(256);
  const long HQ = 131072;  // per-head stride in qkv (8 ch * 16384)
  const long HS = 65536;   // per-head stride in scores/P

  // 0. bf16 conversions (weights + x)
  cvt_kernel<<<8192, blk, 0, stream>>>((const float4*)x, (ushort4*)xbf, 2097152);
  cvt_kernel<<<768,  blk, 0, stream>>>((const float4*)w_row, (ushort4*)wrowb, 196608);
  cvt_kernel<<<768,  blk, 0, stream>>>((const float4*)w_col, (ushort4*)wcolb, 196608);
  cvt_kernel<<<1024, blk, 0, stream>>>((const float4*)w_ff1, (ushort4*)wff1b, 262144);
  cvt_kernel<<<1024, blk, 0, stream>>>((const float4*)w_ff2, (ushort4*)wff2b, 262144);

  // 1. qkv_row = W_row * x + b_row   [1536][16384] bf16
  gemm<0,1,true,false,1,false><<<dim3(128, 12, 1), blk, 0, stream>>>(
      big, wrowb, xbf, b_row, 512, 512, 16384, 16384, 0, 0, 0);
  // 2. scores[h][i][j] = sum_cs Q[cs][i] K[cs][j]
  gemm<1,1,false,false,0,false><<<dim3(2, 2, 64), blk, 0, stream>>>(
      sc, big, big + (long)512 * 16384, nullptr, 512, 256, 256, 256, HQ, HQ, HS);
  // 3. softmax over j -> bf16 P
  softmax_kernel<<<4096, blk, 0, stream>>>(sc, P);
  // 4. row_out[cs][i] = sum_j P[i][j] V[cs][j]  (transposed epilogue)
  gemm<0,0,false,false,0,true><<<dim3(4, 2, 64), blk, 0, stream>>>(
      bufA, P, big + (long)1024 * 16384, nullptr, 256, 256, 256, 256, HS, HQ, HQ);
  // 5. out1 = LN(x + row_out) -> bufB (+ bf16 actbf)
  ln_kernel<true, true><<<256, dim3(1024), 0, stream>>>(bufB, actbf, x, bufA, w_an1, b_an1);
  // 6. qkv_col = W_col * out1 + b_col  -> big (bf16)
  gemm<0,1,true,false,1,false><<<dim3(128, 12, 1), blk, 0, stream>>>(
      big, wcolb, actbf, b_col, 512, 512, 16384, 16384, 0, 0, 0);
  // 7. column attention -> bufA (fp32), XCD-swizzled linear grid
  colattn_kernel<<<4096, blk, 0, stream>>>(big, bufA);
  // 8+9. h = LN(LN(bufB + bufA)*w_an2+b_an2)*w_ln1+b_ln1 -> bufB in-place (+ actbf)
  ln_fuse_kernel<<<256, dim3(1024), 0, stream>>>(bufB, actbf, bufB, bufA,
                                                 w_an2, b_an2, w_ln1, b_ln1);
  // 10. ff1 = relu(W_ff1 * h + b_ff1) -> big [2048][16384] bf16
  gemm<0,1,true,true,1,false><<<dim3(128, 16, 1), blk, 0, stream>>>(
      big, wff1b, actbf, b_ff1, 512, 512, 16384, 16384, 0, 0, 0);
  // 11. ff2 = W_ff2 * ff1 + b_ff2 -> bufA fp32
  gemm<0,1,true,false,0,false><<<dim3(128, 4, 1), blk, 0, stream>>>(
      bufA, wff2b, big, b_ff2, 2048, 2048, 16384, 16384, 0, 0, 0);
  // 12. out = LN(h + ff2) -> d_out
  ln_kernel<true, false><<<256, dim3(1024), 0, stream>>>(outp, nullptr, bufB, bufA, w_ln2, b_ln2);
}

// Round 7
// 477.822 us; speedup vs baseline: 2.1684x; 1.0446x over previous
//
#include <hip/hip_runtime.h>
#include <hip/hip_bf16.h>

using s16x8 = __attribute__((ext_vector_type(8))) short;   // MFMA bf16 A/B fragment
using f32x4 = __attribute__((ext_vector_type(4))) float;   // MFMA C/D fragment
using u32x2 = __attribute__((ext_vector_type(2))) unsigned;

__device__ __forceinline__ ushort f2bf(float f) {
  union { float f; unsigned u; } v; v.f = f;
  unsigned r = v.u + 0x7fffu + ((v.u >> 16) & 1u);   // RNE
  return (ushort)(r >> 16);
}
__device__ __forceinline__ float bf2f(ushort u) {
  return __uint_as_float(((unsigned)u) << 16);
}
__device__ __forceinline__ void gload16(const void* g, void* l) {
  __builtin_amdgcn_global_load_lds(
      (const __attribute__((address_space(1))) void*)g,
      (__attribute__((address_space(3))) void*)l, 16, 0, 0);
}

// ---------------------------------------------------------------------------
// Universal bf16 GEMM: C[m][n] = sum_k A'[m][k] * B'[n][k]
//   form 0 (N-form): operand stored [rows][K], reg-staged (T14 split)
//   form 1 (T-form): operand stored [K][rows], global_load_lds -> [nb][32k][16]
//                    subtiles, fragments via ds_read_b64_tr_b16 (HW transpose).
// Both paths share the permuted k-map (kg,j) -> {4kg+j, 16+4kg+j}.
// 128x128 tile, 4 waves 2x2, BK=32, 1 barrier/iter, stage(t+1) || compute(t).
// XCD chunking: when gx%8==0, XCD x owns n-blocks [x*gx/8,..) for ALL m,
// m fastest (B column-slice stays XCD-L2-resident; fetched from HBM once
// chip-wide). Else fall back to m-major swizzle / identity.
// ---------------------------------------------------------------------------
template<int AF, int BF, bool BIAS, bool RELU, int OUT, bool TRC>
__global__ __launch_bounds__(256, 3)
void gemm(void* __restrict__ Cv, const ushort* __restrict__ A,
          const ushort* __restrict__ B, const float* __restrict__ bias,
          int K, int lda, int ldb, int ldc, long sA, long sB, long sC)
{
  __shared__ ushort As[2][5120];   // N-form: [128][40] padded; T-form: [8][512]
  __shared__ ushort Bs[2][5120];
  const int tid  = threadIdx.x;
  const int lane = tid & 63, wid = tid >> 6;
  const int gx = gridDim.x, gy = gridDim.y;
  const int lin = blockIdx.y * gx + blockIdx.x;
  int mb, nb;
  if ((gx & 7) == 0) {             // n-major XCD chunking (T1 fixed)
    const int xcd = lin & 7, idx = lin >> 3, gxp = gx >> 3;
    nb = xcd * gxp + idx / gy;
    mb = idx % gy;
  } else {
    const int nwg = gx * gy;
    const int swz = ((nwg & 7) == 0) ? ((lin & 7) * (nwg >> 3) + (lin >> 3)) : lin;
    mb = swz / gx; nb = swz % gx;
  }
  const int m0 = mb * 128, n0 = nb * 128;
  A += (long)blockIdx.z * sA;
  B += (long)blockIdx.z * sB;

  const int wm = (wid >> 1) * 64, wn = (wid & 1) * 64;
  const int fr = lane & 15, kg = lane >> 4;

  f32x4 acc[4][4];
#pragma unroll
  for (int i = 0; i < 4; ++i)
#pragma unroll
    for (int j = 0; j < 4; ++j)
#pragma unroll
      for (int r = 0; r < 4; ++r) acc[i][j][r] = 0.f;

  auto stageT = [&](const ushort* __restrict__ G, int ld, int c0,
                    ushort* lds, int k0) {
#pragma unroll
    for (int c = 0; c < 2; ++c) {
      const int nb2 = wid * 2 + c;
      const ushort* gp = G + (long)(k0 + (lane >> 1)) * ld + c0 + nb2 * 16 + (lane & 1) * 8;
      gload16(gp, lds + nb2 * 512);
    }
  };
  auto loadN = [&](const ushort* __restrict__ G, int ld, int r0, int k0,
                   uint4& x, uint4& y) {
    const ushort* gp = G + (long)(r0 + (tid >> 1)) * ld + k0 + (tid & 1) * 8;
    x = *(const uint4*)gp;
    y = *(const uint4*)(gp + 16);
  };
  auto writeN = [&](ushort* lds, uint4 x, uint4 y) {
    ushort* p = lds + (tid >> 1) * 40 + (tid & 1) * 8;
    *(uint4*)p = x;
    *(uint4*)(p + 16) = y;
  };
  auto fragN = [&](const ushort* lds, int row) {
    union { s16x8 f; u32x2 h[2]; } u;
    const ushort* p = lds + row * 40 + kg * 4;
    u.h[0] = *(const u32x2*)p;
    u.h[1] = *(const u32x2*)(p + 16);
    return u.f;
  };
  auto fragT = [&](const ushort* lds, int rb) {
    union { s16x8 f; u32x2 h[2]; } u;
    unsigned base = (unsigned)(unsigned long long)(lds + rb * 512) + lane * 8;
    asm volatile("ds_read_b64_tr_b16 %0, %1" : "=v"(u.h[0]) : "v"(base));
    asm volatile("ds_read_b64_tr_b16 %0, %1 offset:512" : "=v"(u.h[1]) : "v"(base));
    return u.f;
  };

  const int NT = K >> 5;
  uint4 ax, ay, bx, by;

  if constexpr (AF == 0) { loadN(A, lda, m0, 0, ax, ay); writeN(As[0], ax, ay); }
  else                   { stageT(A, lda, m0, As[0], 0); }
  if constexpr (BF == 0) { loadN(B, ldb, n0, 0, bx, by); writeN(Bs[0], bx, by); }
  else                   { stageT(B, ldb, n0, Bs[0], 0); }
  __syncthreads();

  for (int t = 0; t < NT; ++t) {
    const int cur = t & 1, nxt = cur ^ 1;
    const bool pre = (t + 1) < NT;
    if (pre) {
      if constexpr (AF == 0) loadN(A, lda, m0, (t + 1) << 5, ax, ay);
      else                   stageT(A, lda, m0, As[nxt], (t + 1) << 5);
      if constexpr (BF == 0) loadN(B, ldb, n0, (t + 1) << 5, bx, by);
      else                   stageT(B, ldb, n0, Bs[nxt], (t + 1) << 5);
    }
    s16x8 af[4], bv[4];
#pragma unroll
    for (int m = 0; m < 4; ++m) {
      if constexpr (AF == 0) af[m] = fragN(As[cur], wm + m * 16 + fr);
      else                   af[m] = fragT(As[cur], (wm >> 4) + m);
    }
#pragma unroll
    for (int n = 0; n < 4; ++n) {
      if constexpr (BF == 0) bv[n] = fragN(Bs[cur], wn + n * 16 + fr);
      else                   bv[n] = fragT(Bs[cur], (wn >> 4) + n);
    }
    if constexpr (AF == 1 || BF == 1) {
      asm volatile("s_waitcnt lgkmcnt(0)");
      __builtin_amdgcn_sched_barrier(0);        // rule #18
    }
    __builtin_amdgcn_s_setprio(1);
#pragma unroll
    for (int m = 0; m < 4; ++m)
#pragma unroll
      for (int n = 0; n < 4; ++n)
        acc[m][n] = __builtin_amdgcn_mfma_f32_16x16x32_bf16(af[m], bv[n], acc[m][n], 0, 0, 0);
    __builtin_amdgcn_s_setprio(0);
    if (pre) {
      if constexpr (AF == 0) writeN(As[nxt], ax, ay);
      if constexpr (BF == 0) writeN(Bs[nxt], bx, by);
    }
    __syncthreads();
  }

  // epilogue. C/D layout (m89/m91): col = lane&15, row = (lane>>4)*4 + reg
#pragma unroll
  for (int m = 0; m < 4; ++m) {
    const int rowb = m0 + wm + m * 16 + kg * 4;
#pragma unroll
    for (int n = 0; n < 4; ++n) {
      const int col = n0 + wn + n * 16 + fr;
      f32x4 v = acc[m][n];
      if constexpr (BIAS) {
#pragma unroll
        for (int r = 0; r < 4; ++r) v[r] += bias[rowb + r];
      }
      if constexpr (RELU) {
#pragma unroll
        for (int r = 0; r < 4; ++r) v[r] = fmaxf(v[r], 0.f);
      }
      if constexpr (TRC) {
        float* C = (float*)Cv + (long)blockIdx.z * sC;
        float4 s; s.x = v[0]; s.y = v[1]; s.z = v[2]; s.w = v[3];
        *(float4*)(C + (long)col * ldc + rowb) = s;
      } else if constexpr (OUT == 0) {
        float* C = (float*)Cv + (long)blockIdx.z * sC;
#pragma unroll
        for (int r = 0; r < 4; ++r) C[(long)(rowb + r) * ldc + col] = v[r];
      } else {
        ushort* C = (ushort*)Cv + (long)blockIdx.z * sC;
#pragma unroll
        for (int r = 0; r < 4; ++r) C[(long)(rowb + r) * ldc + col] = f2bf(v[r]);
      }
    }
  }
}

// fp32 -> bf16 bulk convert
__global__ __launch_bounds__(256)
void cvt_kernel(const float4* __restrict__ in, ushort4* __restrict__ out, int n4) {
  int i = blockIdx.x * 256 + threadIdx.x;
  if (i < n4) {
    float4 f = in[i];
    ushort4 u; u.x = f2bf(f.x); u.y = f2bf(f.y); u.z = f2bf(f.z); u.w = f2bf(f.w);
    out[i] = u;
  }
}

// Row softmax over last dim of [16384][256] fp32 scores -> bf16 P
__global__ __launch_bounds__(256)
void softmax_kernel(const float* __restrict__ S, ushort* __restrict__ P) {
  const int row = blockIdx.x * 4 + (threadIdx.x >> 6);
  const int lane = threadIdx.x & 63;
  float4 v = *(const float4*)(S + (long)row * 256 + lane * 4);
  float mx = fmaxf(fmaxf(v.x, v.y), fmaxf(v.z, v.w));
#pragma unroll
  for (int off = 32; off; off >>= 1) mx = fmaxf(mx, __shfl_xor(mx, off));
  v.x = __expf(v.x - mx); v.y = __expf(v.y - mx);
  v.z = __expf(v.z - mx); v.w = __expf(v.w - mx);
  float s = v.x + v.y + v.z + v.w;
#pragma unroll
  for (int off = 32; off; off >>= 1) s += __shfl_xor(s, off);
  const float r = 1.f / s;
  ushort4 o;
  o.x = f2bf(v.x * r); o.y = f2bf(v.y * r); o.z = f2bf(v.z * r); o.w = f2bf(v.w * r);
  *(ushort4*)(P + (long)row * 256 + lane * 4) = o;
}

// Column attention with XCD swizzle: blocks sharing cache lines (same head,
// adjacent l) land on the same XCD's L2. grid = 4096 linear.
__global__ __launch_bounds__(256)
void colattn_kernel(const ushort* __restrict__ qkv, float* __restrict__ out) {
  __shared__ float q[4][8][64], kk[4][8][64], vv[4][8][64];
  const int lin = blockIdx.x;
  const int swz = (lin & 7) * 512 + (lin >> 3);   // bijective, 4096 % 8 == 0
  const int h = swz >> 6;
  const int l0 = (swz & 63) * 4;
  const int tid = threadIdx.x;
  for (int i = tid; i < 1536; i += 256) {
    int m = i >> 9;              // 0:q 1:k 2:v
    int e = i & 511;             // c*64+s
    int c = e >> 6, s = e & 63;
    ushort4 u = *(const ushort4*)(qkv + (long)(m * 512 + h * 8 + c) * 16384 + s * 256 + l0);
    float* dst = (m == 0) ? &q[0][0][0] : (m == 1) ? &kk[0][0][0] : &vv[0][0][0];
    dst[e] = bf2f(u.x); dst[512 + e] = bf2f(u.y);
    dst[1024 + e] = bf2f(u.z); dst[1536 + e] = bf2f(u.w);
  }
  __syncthreads();
  const int li = tid >> 6, lane = tid & 63;   // lane = query index i (s)
  float qi[8];
#pragma unroll
  for (int c = 0; c < 8; ++c) qi[c] = q[li][c][lane];
  float sc[64];
#pragma unroll
  for (int j = 0; j < 64; ++j) {
    float s = 0.f;
#pragma unroll
    for (int c = 0; c < 8; ++c) s += qi[c] * kk[li][c][j];
    sc[j] = s;
  }
  float mx = sc[0];
#pragma unroll
  for (int j = 1; j < 64; ++j) mx = fmaxf(mx, sc[j]);
  float sum = 0.f;
#pragma unroll
  for (int j = 0; j < 64; ++j) { sc[j] = __expf(sc[j] - mx); sum += sc[j]; }
  const float rs = 1.f / sum;
  float o[8];
#pragma unroll
  for (int c = 0; c < 8; ++c) o[c] = 0.f;
#pragma unroll
  for (int j = 0; j < 64; ++j)
#pragma unroll
    for (int c = 0; c < 8; ++c) o[c] += sc[j] * vv[li][c][j];
#pragma unroll
  for (int c = 0; c < 8; ++c) q[li][c][lane] = o[c] * rs;
  __syncthreads();
  for (int i = tid; i < 512; i += 256) {
    int c = i >> 6, s = i & 63;
    float4 f; f.x = q[0][c][s]; f.y = q[1][c][s]; f.z = q[2][c][s]; f.w = q[3][c][s];
    *(float4*)(out + (long)(h * 8 + c) * 16384 + s * 256 + l0) = f;
  }
}

// Register-resident channel LN: block=1024 (16 segs x 64 lanes), each thread
// holds its 32-channel slice in VGPRs -> input read ONCE, 16 waves/CU.
template<bool RES, bool BFO>
__global__ __launch_bounds__(1024)
void ln_kernel(float* __restrict__ out, ushort* __restrict__ bfo,
               const float* __restrict__ a, const float* __restrict__ b,
               const float* __restrict__ w, const float* __restrict__ bias) {
  __shared__ float red[2][16][64];
  const int lane = threadIdx.x & 63, seg = threadIdx.x >> 6;
  const long n = (long)blockIdx.x * 64 + lane;
  const int d0 = seg * 32;
  float v[32];
  float s1 = 0.f, s2 = 0.f;
#pragma unroll
  for (int i = 0; i < 32; ++i) {
    float t = a[(long)(d0 + i) * 16384 + n];
    if constexpr (RES) t += b[(long)(d0 + i) * 16384 + n];
    v[i] = t; s1 += t; s2 += t * t;
  }
  red[0][seg][lane] = s1; red[1][seg][lane] = s2;
  __syncthreads();
  s1 = 0.f; s2 = 0.f;
#pragma unroll
  for (int s = 0; s < 16; ++s) { s1 += red[0][s][lane]; s2 += red[1][s][lane]; }
  const float mean = s1 * (1.f / 512.f);
  const float var = s2 * (1.f / 512.f) - mean * mean;
  const float rstd = rsqrtf(var + 1e-5f);
#pragma unroll
  for (int i = 0; i < 32; ++i) {
    float o = (v[i] - mean) * rstd * w[d0 + i] + bias[d0 + i];
    out[(long)(d0 + i) * 16384 + n] = o;
    if constexpr (BFO) bfo[(long)(d0 + i) * 16384 + n] = f2bf(o);
  }
}

// Fused LN8+LN9: h = LN( LN(a+b)*w1+b1 )*w2+b2, in-place capable, + bf16 copy.
__global__ __launch_bounds__(1024)
void ln_fuse_kernel(float* __restrict__ out, ushort* __restrict__ bfo,
                    const float* __restrict__ a, const float* __restrict__ b,
                    const float* __restrict__ w1, const float* __restrict__ b1,
                    const float* __restrict__ w2, const float* __restrict__ b2) {
  __shared__ float red[2][16][64];
  const int lane = threadIdx.x & 63, seg = threadIdx.x >> 6;
  const long n = (long)blockIdx.x * 64 + lane;
  const int d0 = seg * 32;
  float v[32];
  float s1 = 0.f, s2 = 0.f;
#pragma unroll
  for (int i = 0; i < 32; ++i) {
    float t = a[(long)(d0 + i) * 16384 + n] + b[(long)(d0 + i) * 16384 + n];
    v[i] = t; s1 += t; s2 += t * t;
  }
  red[0][seg][lane] = s1; red[1][seg][lane] = s2;
  __syncthreads();
  s1 = 0.f; s2 = 0.f;
#pragma unroll
  for (int s = 0; s < 16; ++s) { s1 += red[0][s][lane]; s2 += red[1][s][lane]; }
  float mean = s1 * (1.f / 512.f);
  float var = s2 * (1.f / 512.f) - mean * mean;
  float rstd = rsqrtf(var + 1e-5f);
  __syncthreads();   // red reuse
  s1 = 0.f; s2 = 0.f;
#pragma unroll
  for (int i = 0; i < 32; ++i) {
    float y = (v[i] - mean) * rstd * w1[d0 + i] + b1[d0 + i];
    v[i] = y; s1 += y; s2 += y * y;
  }
  red[0][seg][lane] = s1; red[1][seg][lane] = s2;
  __syncthreads();
  s1 = 0.f; s2 = 0.f;
#pragma unroll
  for (int s = 0; s < 16; ++s) { s1 += red[0][s][lane]; s2 += red[1][s][lane]; }
  mean = s1 * (1.f / 512.f);
  var = s2 * (1.f / 512.f) - mean * mean;
  rstd = rsqrtf(var + 1e-5f);
#pragma unroll
  for (int i = 0; i < 32; ++i) {
    float o = (v[i] - mean) * rstd * w2[d0 + i] + b2[d0 + i];
    out[(long)(d0 + i) * 16384 + n] = o;
    bfo[(long)(d0 + i) * 16384 + n] = f2bf(o);
  }
}

extern "C" void kernel_launch(void* const* d_in, const int* in_sizes, int n_in,
                              void* d_out, int out_size, void* d_ws, size_t ws_size,
                              hipStream_t stream) {
  const float* x     = (const float*)d_in[0];
  const float* w_row = (const float*)d_in[1];
  const float* b_row = (const float*)d_in[2];
  const float* w_col = (const float*)d_in[3];
  const float* b_col = (const float*)d_in[4];
  const float* w_an1 = (const float*)d_in[5];
  const float* b_an1 = (const float*)d_in[6];
  const float* w_an2 = (const float*)d_in[7];
  const float* b_an2 = (const float*)d_in[8];
  const float* w_ff1 = (const float*)d_in[9];
  const float* b_ff1 = (const float*)d_in[10];
  const float* w_ff2 = (const float*)d_in[11];
  const float* b_ff2 = (const float*)d_in[12];
  const float* w_ln1 = (const float*)d_in[13];
  const float* b_ln1 = (const float*)d_in[14];
  const float* w_ln2 = (const float*)d_in[15];
  const float* b_ln2 = (const float*)d_in[16];
  float* outp = (float*)d_out;

  char* Wb = (char*)d_ws;
  ushort* big   = (ushort*)Wb;                              // [2048][16384] bf16: qkv, then ff1
  float*  sc    = (float*)(Wb + (size_t)1536 * 16384 * 2);  // scores fp32
  float*  bufA  = (float*)(Wb + 67108864ull);               // 32 MiB fp32 [512][16384]
  float*  bufB  = (float*)(Wb + 100663296ull);              // 32 MiB
  ushort* P     = (ushort*)(Wb + 134217728ull);             // bf16 attn probs
  ushort* actbf = (ushort*)(Wb + 167772160ull);             // 16 MiB bf16 act / x_bf
  ushort* xbf   = actbf;
  ushort* wrowb = (ushort*)(Wb + 184549376ull);
  ushort* wcolb = wrowb + 786432;
  ushort* wff1b = wcolb + 786432;
  ushort* wff2b = wff1b + 1048576;

  const dim3 blk(256);
  const long HQ = 131072;  // per-head stride in qkv (8 ch * 16384)
  const long HS = 65536;   // per-head stride in scores/P

  // 0. bf16 conversions (weights + x)
  cvt_kernel<<<8192, blk, 0, stream>>>((const float4*)x, (ushort4*)xbf, 2097152);
  cvt_kernel<<<768,  blk, 0, stream>>>((const float4*)w_row, (ushort4*)wrowb, 196608);
  cvt_kernel<<<768,  blk, 0, stream>>>((const float4*)w_col, (ushort4*)wcolb, 196608);
  cvt_kernel<<<1024, blk, 0, stream>>>((const float4*)w_ff1, (ushort4*)wff1b, 262144);
  cvt_kernel<<<1024, blk, 0, stream>>>((const float4*)w_ff2, (ushort4*)wff2b, 262144);

  // 1. qkv_row = W_row * x + b_row   [1536][16384] bf16
  gemm<0,1,true,false,1,false><<<dim3(128, 12, 1), blk, 0, stream>>>(
      big, wrowb, xbf, b_row, 512, 512, 16384, 16384, 0, 0, 0);
  // 2. scores[h][i][j] = sum_cs Q[cs][i] K[cs][j]
  gemm<1,1,false,false,0,false><<<dim3(2, 2, 64), blk, 0, stream>>>(
      sc, big, big + (long)512 * 16384, nullptr, 512, 256, 256, 256, HQ, HQ, HS);
  // 3. softmax over j -> bf16 P
  softmax_kernel<<<4096, blk, 0, stream>>>(sc, P);
  // 4. row_out[cs][i] = sum_j P[i][j] V[cs][j]  (transposed epilogue)
  gemm<0,0,false,false,0,true><<<dim3(4, 2, 64), blk, 0, stream>>>(
      bufA, P, big + (long)1024 * 16384, nullptr, 256, 256, 256, 256, HS, HQ, HQ);
  // 5. out1 = LN(x + row_out) -> bufB (+ bf16 actbf)
  ln_kernel<true, true><<<256, dim3(1024), 0, stream>>>(bufB, actbf, x, bufA, w_an1, b_an1);
  // 6. qkv_col = W_col * out1 + b_col  -> big (bf16)
  gemm<0,1,true,false,1,false><<<dim3(128, 12, 1), blk, 0, stream>>>(
      big, wcolb, actbf, b_col, 512, 512, 16384, 16384, 0, 0, 0);
  // 7. column attention -> bufA (fp32), XCD-swizzled linear grid
  colattn_kernel<<<4096, blk, 0, stream>>>(big, bufA);
  // 8+9. h = LN(LN(bufB + bufA)*w_an2+b_an2)*w_ln1+b_ln1 -> bufB in-place (+ actbf)
  ln_fuse_kernel<<<256, dim3(1024), 0, stream>>>(bufB, actbf, bufB, bufA,
                                                 w_an2, b_an2, w_ln1, b_ln1);
  // 10. ff1 = relu(W_ff1 * h + b_ff1) -> big [2048][16384] bf16
  gemm<0,1,true,true,1,false><<<dim3(128, 16, 1), blk, 0, stream>>>(
      big, wff1b, actbf, b_ff1, 512, 512, 16384, 16384, 0, 0, 0);
  // 11. ff2 = W_ff2 * ff1 + b_ff2 -> bufA fp32
  gemm<0,1,true,false,0,false><<<dim3(128, 4, 1), blk, 0, stream>>>(
      bufA, wff2b, big, b_ff2, 2048, 2048, 16384, 16384, 0, 0, 0);
  // 12. out = LN(h + ff2) -> d_out
  ln_kernel<true, false><<<256, dim3(1024), 0, stream>>>(outp, nullptr, bufB, bufA, w_ln2, b_ln2);
}

// Round 9
// 433.674 us; speedup vs baseline: 2.3892x; 1.1018x over previous
//
#include <hip/hip_runtime.h>
#include <hip/hip_bf16.h>

using s16x8 = __attribute__((ext_vector_type(8))) short;   // MFMA bf16 A/B fragment
using f32x4 = __attribute__((ext_vector_type(4))) float;   // MFMA C/D fragment
using u32x2 = __attribute__((ext_vector_type(2))) unsigned;

__device__ __forceinline__ ushort f2bf(float f) {
  union { float f; unsigned u; } v; v.f = f;
  unsigned r = v.u + 0x7fffu + ((v.u >> 16) & 1u);   // RNE
  return (ushort)(r >> 16);
}
__device__ __forceinline__ float bf2f(ushort u) {
  return __uint_as_float(((unsigned)u) << 16);
}
__device__ __forceinline__ void gload16(const void* g, void* l) {
  __builtin_amdgcn_global_load_lds(
      (const __attribute__((address_space(1))) void*)g,
      (__attribute__((address_space(3))) void*)l, 16, 0, 0);
}

// ---------------------------------------------------------------------------
// Universal bf16 GEMM (inner loop frozen since r3; epilogue grew bf16-TRC).
// C[m][n] = sum_k A'[m][k] * B'[n][k]
//   form 0: operand stored [rows][K], reg-staged. form 1: [K][rows],
//   global_load_lds -> [nb][32k][16] subtiles, ds_read_b64_tr_b16 fragments.
// 128x128 tile, 4 waves, BK=32, 1 barrier/iter, stage(t+1) || compute(t).
// n-major XCD chunking when gx%8==0 (B column-slice XCD-L2-resident).
// OUT: 0 fp32, 1 bf16. TRC: transposed epilogue C[n][m].
// ---------------------------------------------------------------------------
template<int AF, int BF, bool BIAS, bool RELU, int OUT, bool TRC>
__global__ __launch_bounds__(256, 3)
void gemm(void* __restrict__ Cv, const ushort* __restrict__ A,
          const ushort* __restrict__ B, const float* __restrict__ bias,
          int K, int lda, int ldb, int ldc, long sA, long sB, long sC)
{
  __shared__ ushort As[2][5120];
  __shared__ ushort Bs[2][5120];
  const int tid  = threadIdx.x;
  const int lane = tid & 63, wid = tid >> 6;
  const int gx = gridDim.x, gy = gridDim.y;
  const int lin = blockIdx.y * gx + blockIdx.x;
  int mb, nb;
  if ((gx & 7) == 0) {             // n-major XCD chunking
    const int xcd = lin & 7, idx = lin >> 3, gxp = gx >> 3;
    nb = xcd * gxp + idx / gy;
    mb = idx % gy;
  } else {
    const int nwg = gx * gy;
    const int swz = ((nwg & 7) == 0) ? ((lin & 7) * (nwg >> 3) + (lin >> 3)) : lin;
    mb = swz / gx; nb = swz % gx;
  }
  const int m0 = mb * 128, n0 = nb * 128;
  A += (long)blockIdx.z * sA;
  B += (long)blockIdx.z * sB;

  const int wm = (wid >> 1) * 64, wn = (wid & 1) * 64;
  const int fr = lane & 15, kg = lane >> 4;

  f32x4 acc[4][4];
#pragma unroll
  for (int i = 0; i < 4; ++i)
#pragma unroll
    for (int j = 0; j < 4; ++j)
#pragma unroll
      for (int r = 0; r < 4; ++r) acc[i][j][r] = 0.f;

  auto stageT = [&](const ushort* __restrict__ G, int ld, int c0,
                    ushort* lds, int k0) {
#pragma unroll
    for (int c = 0; c < 2; ++c) {
      const int nb2 = wid * 2 + c;
      const ushort* gp = G + (long)(k0 + (lane >> 1)) * ld + c0 + nb2 * 16 + (lane & 1) * 8;
      gload16(gp, lds + nb2 * 512);
    }
  };
  auto loadN = [&](const ushort* __restrict__ G, int ld, int r0, int k0,
                   uint4& x, uint4& y) {
    const ushort* gp = G + (long)(r0 + (tid >> 1)) * ld + k0 + (tid & 1) * 8;
    x = *(const uint4*)gp;
    y = *(const uint4*)(gp + 16);
  };
  auto writeN = [&](ushort* lds, uint4 x, uint4 y) {
    ushort* p = lds + (tid >> 1) * 40 + (tid & 1) * 8;
    *(uint4*)p = x;
    *(uint4*)(p + 16) = y;
  };
  auto fragN = [&](const ushort* lds, int row) {
    union { s16x8 f; u32x2 h[2]; } u;
    const ushort* p = lds + row * 40 + kg * 4;
    u.h[0] = *(const u32x2*)p;
    u.h[1] = *(const u32x2*)(p + 16);
    return u.f;
  };
  auto fragT = [&](const ushort* lds, int rb) {
    union { s16x8 f; u32x2 h[2]; } u;
    unsigned base = (unsigned)(unsigned long long)(lds + rb * 512) + lane * 8;
    asm volatile("ds_read_b64_tr_b16 %0, %1" : "=v"(u.h[0]) : "v"(base));
    asm volatile("ds_read_b64_tr_b16 %0, %1 offset:512" : "=v"(u.h[1]) : "v"(base));
    return u.f;
  };

  const int NT = K >> 5;
  uint4 ax, ay, bx, by;

  if constexpr (AF == 0) { loadN(A, lda, m0, 0, ax, ay); writeN(As[0], ax, ay); }
  else                   { stageT(A, lda, m0, As[0], 0); }
  if constexpr (BF == 0) { loadN(B, ldb, n0, 0, bx, by); writeN(Bs[0], bx, by); }
  else                   { stageT(B, ldb, n0, Bs[0], 0); }
  __syncthreads();

  for (int t = 0; t < NT; ++t) {
    const int cur = t & 1, nxt = cur ^ 1;
    const bool pre = (t + 1) < NT;
    if (pre) {
      if constexpr (AF == 0) loadN(A, lda, m0, (t + 1) << 5, ax, ay);
      else                   stageT(A, lda, m0, As[nxt], (t + 1) << 5);
      if constexpr (BF == 0) loadN(B, ldb, n0, (t + 1) << 5, bx, by);
      else                   stageT(B, ldb, n0, Bs[nxt], (t + 1) << 5);
    }
    s16x8 af[4], bv[4];
#pragma unroll
    for (int m = 0; m < 4; ++m) {
      if constexpr (AF == 0) af[m] = fragN(As[cur], wm + m * 16 + fr);
      else                   af[m] = fragT(As[cur], (wm >> 4) + m);
    }
#pragma unroll
    for (int n = 0; n < 4; ++n) {
      if constexpr (BF == 0) bv[n] = fragN(Bs[cur], wn + n * 16 + fr);
      else                   bv[n] = fragT(Bs[cur], (wn >> 4) + n);
    }
    if constexpr (AF == 1 || BF == 1) {
      asm volatile("s_waitcnt lgkmcnt(0)");
      __builtin_amdgcn_sched_barrier(0);        // rule #18
    }
    __builtin_amdgcn_s_setprio(1);
#pragma unroll
    for (int m = 0; m < 4; ++m)
#pragma unroll
      for (int n = 0; n < 4; ++n)
        acc[m][n] = __builtin_amdgcn_mfma_f32_16x16x32_bf16(af[m], bv[n], acc[m][n], 0, 0, 0);
    __builtin_amdgcn_s_setprio(0);
    if (pre) {
      if constexpr (AF == 0) writeN(As[nxt], ax, ay);
      if constexpr (BF == 0) writeN(Bs[nxt], bx, by);
    }
    __syncthreads();
  }

  // epilogue. C/D layout (m89/m91): col = lane&15, row = (lane>>4)*4 + reg
#pragma unroll
  for (int m = 0; m < 4; ++m) {
    const int rowb = m0 + wm + m * 16 + kg * 4;
#pragma unroll
    for (int n = 0; n < 4; ++n) {
      const int col = n0 + wn + n * 16 + fr;
      f32x4 v = acc[m][n];
      if constexpr (BIAS) {
#pragma unroll
        for (int r = 0; r < 4; ++r) v[r] += bias[rowb + r];
      }
      if constexpr (RELU) {
#pragma unroll
        for (int r = 0; r < 4; ++r) v[r] = fmaxf(v[r], 0.f);
      }
      if constexpr (TRC) {
        if constexpr (OUT == 0) {
          float* C = (float*)Cv + (long)blockIdx.z * sC;
          float4 s; s.x = v[0]; s.y = v[1]; s.z = v[2]; s.w = v[3];
          *(float4*)(C + (long)col * ldc + rowb) = s;
        } else {
          ushort* C = (ushort*)Cv + (long)blockIdx.z * sC;
          ushort4 s; s.x = f2bf(v[0]); s.y = f2bf(v[1]); s.z = f2bf(v[2]); s.w = f2bf(v[3]);
          *(ushort4*)(C + (long)col * ldc + rowb) = s;   // rowb%4==0 -> 8B aligned
        }
      } else if constexpr (OUT == 0) {
        float* C = (float*)Cv + (long)blockIdx.z * sC;
#pragma unroll
        for (int r = 0; r < 4; ++r) C[(long)(rowb + r) * ldc + col] = v[r];
      } else {
        ushort* C = (ushort*)Cv + (long)blockIdx.z * sC;
#pragma unroll
        for (int r = 0; r < 4; ++r) C[(long)(rowb + r) * ldc + col] = f2bf(v[r]);
      }
    }
  }
}

// fp32 -> bf16 bulk convert
__global__ __launch_bounds__(256)
void cvt_kernel(const float4* __restrict__ in, ushort4* __restrict__ out, int n4) {
  int i = blockIdx.x * 256 + threadIdx.x;
  if (i < n4) {
    float4 f = in[i];
    ushort4 u; u.x = f2bf(f.x); u.y = f2bf(f.y); u.z = f2bf(f.z); u.w = f2bf(f.w);
    out[i] = u;
  }
}

// Row softmax over last dim of [16384][256] fp32 scores -> bf16 P
__global__ __launch_bounds__(256)
void softmax_kernel(const float* __restrict__ S, ushort* __restrict__ P) {
  const int row = blockIdx.x * 4 + (threadIdx.x >> 6);
  const int lane = threadIdx.x & 63;
  float4 v = *(const float4*)(S + (long)row * 256 + lane * 4);
  float mx = fmaxf(fmaxf(v.x, v.y), fmaxf(v.z, v.w));
#pragma unroll
  for (int off = 32; off; off >>= 1) mx = fmaxf(mx, __shfl_xor(mx, off));
  v.x = __expf(v.x - mx); v.y = __expf(v.y - mx);
  v.z = __expf(v.z - mx); v.w = __expf(v.w - mx);
  float s = v.x + v.y + v.z + v.w;
#pragma unroll
  for (int off = 32; off; off >>= 1) s += __shfl_xor(s, off);
  const float r = 1.f / s;
  ushort4 o;
  o.x = f2bf(v.x * r); o.y = f2bf(v.y * r); o.z = f2bf(v.z * r); o.w = f2bf(v.w * r);
  *(ushort4*)(P + (long)row * 256 + lane * 4) = o;
}

// Column attention, XCD-swizzled. float4 LDS reads (j-contiguous layout):
// 256 b128 reads/thread instead of 1024 b32 -> LDS-issue cut ~4x. bf16 out.
__global__ __launch_bounds__(256)
void colattn_kernel(const ushort* __restrict__ qkv, ushort* __restrict__ out) {
  __shared__ float q[4][8][64], kk[4][8][64], vv[4][8][64];
  const int lin = blockIdx.x;
  const int swz = (lin & 7) * 512 + (lin >> 3);   // bijective, 4096 % 8 == 0
  const int h = swz >> 6;
  const int l0 = (swz & 63) * 4;
  const int tid = threadIdx.x;
  for (int i = tid; i < 1536; i += 256) {
    int m = i >> 9;              // 0:q 1:k 2:v
    int e = i & 511;             // c*64+s
    int c = e >> 6, s = e & 63;
    ushort4 u = *(const ushort4*)(qkv + (long)(m * 512 + h * 8 + c) * 16384 + s * 256 + l0);
    float* dst = (m == 0) ? &q[0][0][0] : (m == 1) ? &kk[0][0][0] : &vv[0][0][0];
    dst[e] = bf2f(u.x); dst[512 + e] = bf2f(u.y);
    dst[1024 + e] = bf2f(u.z); dst[1536 + e] = bf2f(u.w);
  }
  __syncthreads();
  const int li = tid >> 6, lane = tid & 63;   // lane = query index i (s)
  float qi[8];
#pragma unroll
  for (int c = 0; c < 8; ++c) qi[c] = q[li][c][lane];
  float sc[64];
#pragma unroll
  for (int j4 = 0; j4 < 16; ++j4) {
    float ax = 0.f, ay = 0.f, az = 0.f, aw = 0.f;
#pragma unroll
    for (int c = 0; c < 8; ++c) {
      float4 k4 = *(const float4*)&kk[li][c][j4 * 4];   // wave-uniform broadcast
      ax = fmaf(qi[c], k4.x, ax); ay = fmaf(qi[c], k4.y, ay);
      az = fmaf(qi[c], k4.z, az); aw = fmaf(qi[c], k4.w, aw);
    }
    sc[j4 * 4 + 0] = ax; sc[j4 * 4 + 1] = ay;
    sc[j4 * 4 + 2] = az; sc[j4 * 4 + 3] = aw;
  }
  float mx = sc[0];
#pragma unroll
  for (int j = 1; j < 64; ++j) mx = fmaxf(mx, sc[j]);
  float sum = 0.f;
#pragma unroll
  for (int j = 0; j < 64; ++j) { sc[j] = __expf(sc[j] - mx); sum += sc[j]; }
  const float rs = 1.f / sum;
  float o[8];
#pragma unroll
  for (int c = 0; c < 8; ++c) o[c] = 0.f;
#pragma unroll
  for (int j4 = 0; j4 < 16; ++j4) {
    const float px = sc[j4 * 4 + 0], py = sc[j4 * 4 + 1];
    const float pz = sc[j4 * 4 + 2], pw = sc[j4 * 4 + 3];
#pragma unroll
    for (int c = 0; c < 8; ++c) {
      float4 v4 = *(const float4*)&vv[li][c][j4 * 4];
      o[c] = fmaf(px, v4.x, fmaf(py, v4.y, fmaf(pz, v4.z, fmaf(pw, v4.w, o[c]))));
    }
  }
#pragma unroll
  for (int c = 0; c < 8; ++c) q[li][c][lane] = o[c] * rs;
  __syncthreads();
  for (int i = tid; i < 512; i += 256) {
    int c = i >> 6, s = i & 63;
    ushort4 u;
    u.x = f2bf(q[0][c][s]); u.y = f2bf(q[1][c][s]);
    u.z = f2bf(q[2][c][s]); u.w = f2bf(q[3][c][s]);
    *(ushort4*)(out + (long)(h * 8 + c) * 16384 + s * 256 + l0) = u;
  }
}

// Channel LN, bf16 in/out (fp32 math). OM: 0 = bf16 out, 1 = fp32 out.
// Block = 1024 (16 segs x 64 lanes), 32-channel slice in VGPRs, input read once.
template<bool RES, int OM>
__global__ __launch_bounds__(1024)
void ln_kernel(void* __restrict__ outv, const ushort* __restrict__ a,
               const ushort* __restrict__ b, const float* __restrict__ w,
               const float* __restrict__ bias) {
  __shared__ float red[2][16][64];
  const int lane = threadIdx.x & 63, seg = threadIdx.x >> 6;
  const long n = (long)blockIdx.x * 64 + lane;
  const int d0 = seg * 32;
  float v[32];
  float s1 = 0.f, s2 = 0.f;
#pragma unroll
  for (int i = 0; i < 32; ++i) {
    float t = bf2f(a[(long)(d0 + i) * 16384 + n]);
    if constexpr (RES) t += bf2f(b[(long)(d0 + i) * 16384 + n]);
    v[i] = t; s1 += t; s2 += t * t;
  }
  red[0][seg][lane] = s1; red[1][seg][lane] = s2;
  __syncthreads();
  s1 = 0.f; s2 = 0.f;
#pragma unroll
  for (int s = 0; s < 16; ++s) { s1 += red[0][s][lane]; s2 += red[1][s][lane]; }
  const float mean = s1 * (1.f / 512.f);
  const float var = s2 * (1.f / 512.f) - mean * mean;
  const float rstd = rsqrtf(var + 1e-5f);
#pragma unroll
  for (int i = 0; i < 32; ++i) {
    float o = (v[i] - mean) * rstd * w[d0 + i] + bias[d0 + i];
    if constexpr (OM == 0) ((ushort*)outv)[(long)(d0 + i) * 16384 + n] = f2bf(o);
    else                   ((float*)outv)[(long)(d0 + i) * 16384 + n] = o;
  }
}

// Fused LN8+LN9: out = LN( LN(a+b)*w1+b1 )*w2+b2, bf16 in/out.
__global__ __launch_bounds__(1024)
void ln_fuse_kernel(ushort* __restrict__ out, const ushort* __restrict__ a,
                    const ushort* __restrict__ b,
                    const float* __restrict__ w1, const float* __restrict__ b1,
                    const float* __restrict__ w2, const float* __restrict__ b2) {
  __shared__ float red[2][16][64];
  const int lane = threadIdx.x & 63, seg = threadIdx.x >> 6;
  const long n = (long)blockIdx.x * 64 + lane;
  const int d0 = seg * 32;
  float v[32];
  float s1 = 0.f, s2 = 0.f;
#pragma unroll
  for (int i = 0; i < 32; ++i) {
    float t = bf2f(a[(long)(d0 + i) * 16384 + n]) + bf2f(b[(long)(d0 + i) * 16384 + n]);
    v[i] = t; s1 += t; s2 += t * t;
  }
  red[0][seg][lane] = s1; red[1][seg][lane] = s2;
  __syncthreads();
  s1 = 0.f; s2 = 0.f;
#pragma unroll
  for (int s = 0; s < 16; ++s) { s1 += red[0][s][lane]; s2 += red[1][s][lane]; }
  float mean = s1 * (1.f / 512.f);
  float var = s2 * (1.f / 512.f) - mean * mean;
  float rstd = rsqrtf(var + 1e-5f);
  __syncthreads();   // red reuse
  s1 = 0.f; s2 = 0.f;
#pragma unroll
  for (int i = 0; i < 32; ++i) {
    float y = (v[i] - mean) * rstd * w1[d0 + i] + b1[d0 + i];
    v[i] = y; s1 += y; s2 += y * y;
  }
  red[0][seg][lane] = s1; red[1][seg][lane] = s2;
  __syncthreads();
  s1 = 0.f; s2 = 0.f;
#pragma unroll
  for (int s = 0; s < 16; ++s) { s1 += red[0][s][lane]; s2 += red[1][s][lane]; }
  mean = s1 * (1.f / 512.f);
  var = s2 * (1.f / 512.f) - mean * mean;
  rstd = rsqrtf(var + 1e-5f);
#pragma unroll
  for (int i = 0; i < 32; ++i) {
    float o = (v[i] - mean) * rstd * w2[d0 + i] + b2[d0 + i];
    out[(long)(d0 + i) * 16384 + n] = f2bf(o);
  }
}

extern "C" void kernel_launch(void* const* d_in, const int* in_sizes, int n_in,
                              void* d_out, int out_size, void* d_ws, size_t ws_size,
                              hipStream_t stream) {
  const float* x     = (const float*)d_in[0];
  const float* w_row = (const float*)d_in[1];
  const float* b_row = (const float*)d_in[2];
  const float* w_col = (const float*)d_in[3];
  const float* b_col = (const float*)d_in[4];
  const float* w_an1 = (const float*)d_in[5];
  const float* b_an1 = (const float*)d_in[6];
  const float* w_an2 = (const float*)d_in[7];
  const float* b_an2 = (const float*)d_in[8];
  const float* w_ff1 = (const float*)d_in[9];
  const float* b_ff1 = (const float*)d_in[10];
  const float* w_ff2 = (const float*)d_in[11];
  const float* b_ff2 = (const float*)d_in[12];
  const float* w_ln1 = (const float*)d_in[13];
  const float* b_ln1 = (const float*)d_in[14];
  const float* w_ln2 = (const float*)d_in[15];
  const float* b_ln2 = (const float*)d_in[16];
  float* outp = (float*)d_out;

  // ---- workspace (bf16 activation chain), lifetime-packed, ~172 MiB ----
  char* Wb = (char*)d_ws;
  ushort* big    = (ushort*)Wb;                       // [2048][16384] bf16: qkv / ff1
  float*  sc     = (float*)(Wb + 71303168ull);        // 68 MiB: scores fp32 (dead after sm)
  ushort* colbf  = (ushort*)(Wb + 71303168ull);       //   reused: col-attn out (step 7+)
  ushort* P      = (ushort*)(Wb + 90177536ull);       // 86 MiB: bf16 probs
  ushort* xbf    = (ushort*)(Wb + 100663296ull);      // 96 MiB: x bf16 (dead after ln5)
  ushort* ff2bf  = (ushort*)(Wb + 100663296ull);      //   reused: ff2 out (step 11+)
  ushort* rowbf  = (ushort*)(Wb + 118489088ull);      // 113 MiB: row-attn out bf16
  ushort* out1bf = (ushort*)(Wb + 136314880ull);      // 130 MiB: LN5 out bf16
  ushort* hbf    = (ushort*)(Wb + 154140672ull);      // 147 MiB: fused-LN out bf16
  ushort* wrowb  = (ushort*)(Wb + 171966464ull);      // 164 MiB: weights bf16
  ushort* wcolb = wrowb + 786432;
  ushort* wff1b = wcolb + 786432;
  ushort* wff2b = wff1b + 1048576;

  const dim3 blk(256);
  const long HQ = 131072;  // per-head stride in qkv (8 ch * 16384)
  const long HS = 65536;   // per-head stride in scores/P

  // 0. bf16 conversions (x + weights)
  cvt_kernel<<<8192, blk, 0, stream>>>((const float4*)x, (ushort4*)xbf, 2097152);
  cvt_kernel<<<768,  blk, 0, stream>>>((const float4*)w_row, (ushort4*)wrowb, 196608);
  cvt_kernel<<<768,  blk, 0, stream>>>((const float4*)w_col, (ushort4*)wcolb, 196608);
  cvt_kernel<<<1024, blk, 0, stream>>>((const float4*)w_ff1, (ushort4*)wff1b, 262144);
  cvt_kernel<<<1024, blk, 0, stream>>>((const float4*)w_ff2, (ushort4*)wff2b, 262144);

  // 1. qkv_row = W_row * x + b_row   [1536][16384] bf16
  gemm<0,1,true,false,1,false><<<dim3(128, 12, 1), blk, 0, stream>>>(
      big, wrowb, xbf, b_row, 512, 512, 16384, 16384, 0, 0, 0);
  // 2. scores[h][i][j] = sum_cs Q[cs][i] K[cs][j]
  gemm<1,1,false,false,0,false><<<dim3(2, 2, 64), blk, 0, stream>>>(
      sc, big, big + (long)512 * 16384, nullptr, 512, 256, 256, 256, HQ, HQ, HS);
  // 3. softmax over j -> bf16 P
  softmax_kernel<<<4096, blk, 0, stream>>>(sc, P);
  // 4. row_out[cs][i] = sum_j P[i][j] V[cs][j]  (bf16 transposed epilogue)
  gemm<0,0,false,false,1,true><<<dim3(4, 2, 64), blk, 0, stream>>>(
      rowbf, P, big + (long)1024 * 16384, nullptr, 256, 256, 256, 256, HS, HQ, HQ);
  // 5. out1 = LN(x + row_out) -> out1bf
  ln_kernel<true, 0><<<256, dim3(1024), 0, stream>>>(out1bf, xbf, rowbf, w_an1, b_an1);
  // 6. qkv_col = W_col * out1 + b_col  -> big (bf16)
  gemm<0,1,true,false,1,false><<<dim3(128, 12, 1), blk, 0, stream>>>(
      big, wcolb, out1bf, b_col, 512, 512, 16384, 16384, 0, 0, 0);
  // 7. column attention -> colbf
  colattn_kernel<<<4096, blk, 0, stream>>>(big, colbf);
  // 8+9. h = LN(LN(out1 + col_out)*w_an2+b_an2)*w_ln1+b_ln1 -> hbf
  ln_fuse_kernel<<<256, dim3(1024), 0, stream>>>(hbf, out1bf, colbf,
                                                 w_an2, b_an2, w_ln1, b_ln1);
  // 10. ff1 = relu(W_ff1 * h + b_ff1) -> big [2048][16384] bf16
  gemm<0,1,true,true,1,false><<<dim3(128, 16, 1), blk, 0, stream>>>(
      big, wff1b, hbf, b_ff1, 512, 512, 16384, 16384, 0, 0, 0);
  // 11. ff2 = W_ff2 * ff1 + b_ff2 -> ff2bf
  gemm<0,1,true,false,1,false><<<dim3(128, 4, 1), blk, 0, stream>>>(
      ff2bf, wff2b, big, b_ff2, 2048, 2048, 16384, 16384, 0, 0, 0);
  // 12. out = LN(h + ff2) -> d_out (fp32)
  ln_kernel<true, 1><<<256, dim3(1024), 0, stream>>>(outp, hbf, ff2bf, w_ln2, b_ln2);
}